// Round 4
// baseline (1626.805 us; speedup 1.0000x reference)
//
#include <hip/hip_runtime.h>
#include <math.h>

#define Bc 8
#define Nc 4096
#define CINc 128
#define COUTc 256
#define Sc 1024
#define Kc 24
#define TCHc 256
#define Mc 32
#define Hc 4
#define HDc 64
#define MBAT (Sc*Kc)      // rows per batch in Local stage: 24576

#define BN_SCALE_F 0.9999950000374997f

typedef __attribute__((ext_vector_type(8))) short bf16x8;
typedef __attribute__((ext_vector_type(4))) float f32x4;

__device__ __forceinline__ float b2f(short s){
  unsigned int u = ((unsigned int)(unsigned short)s) << 16;
  union { unsigned int u; float f; } c; c.u = u; return c.f;
}
__device__ __forceinline__ short f2b(float f){
  union { unsigned int u; float f; } c; c.f = f;
  unsigned int u = c.u;
  unsigned int r = (u + 0x7fffu + ((u >> 16) & 1u)) >> 16;
  return (short)(r & 0xffffu);
}
__device__ __forceinline__ float gelu_f(float v){
  return 0.5f * v * (1.f + erff(v * 0.7071067811865475f));
}
__device__ __forceinline__ float rdval(const float* p){ return *p; }
__device__ __forceinline__ float rdval(const short* p){ return b2f(*p); }
__device__ __forceinline__ void wrval(float* p, float v){ *p = v; }
__device__ __forceinline__ void wrval(short* p, float v){ *p = f2b(v); }

// async global->LDS, 16B per lane (dest follows lane order: base + lane*16B)
__device__ __forceinline__ void gl_lds16(const short* g, short* l){
  __builtin_amdgcn_global_load_lds(
     (const __attribute__((address_space(1))) void*)g,
     (__attribute__((address_space(3))) void*)l, 16, 0, 0);
}

// barrier that drains ONLY LDS ops (lgkmcnt), leaving global stores in flight.
__device__ __forceinline__ void bar_lds(){
  asm volatile("s_waitcnt lgkmcnt(0)" ::: "memory");
  __builtin_amdgcn_s_barrier();
}

// ---- packed-key helpers: (f32 bits << 32) | tag  as positive f64 ----------
__device__ __forceinline__ double packkey(float d, unsigned tag){
  return __longlong_as_double((long long)(
    (((unsigned long long)(unsigned)__float_as_int(d)) << 32) | (unsigned long long)tag));
}
__device__ __forceinline__ double pack2f(float a, float b){
  return __longlong_as_double((long long)(
    (((unsigned long long)(unsigned)__float_as_int(b)) << 32) | (unsigned)__float_as_int(a)));
}

template<int CTRL>
__device__ __forceinline__ double dpp_mov_f64(double v){
  long long x = __double_as_longlong(v);
  int lo = (int)(unsigned)(x & 0xFFFFFFFFLL);
  int hi = (int)(unsigned)((unsigned long long)x >> 32);
  int plo = __builtin_amdgcn_update_dpp(lo, lo, CTRL, 0xF, 0xF, false);
  int phi = __builtin_amdgcn_update_dpp(hi, hi, CTRL, 0xF, 0xF, false);
  return __longlong_as_double((long long)(((unsigned long long)(unsigned)phi << 32)
                                          | (unsigned)plo));
}
template<int CTRL>
__device__ __forceinline__ float dpp_mov_f32(float v){
  int p = __builtin_amdgcn_update_dpp(__float_as_int(v), __float_as_int(v), CTRL, 0xF, 0xF, false);
  return __int_as_float(p);
}
template<int CTRL>
__device__ __forceinline__ double dpp_min_f64(double v){
  return fmin(v, dpp_mov_f64<CTRL>(v));
}
// merge top-2 pairs across lanes; coords follow top-1.
// All merges in the shr/bcast ladder are DISJOINT or SELF; keys are unique per
// element (tag in low bits), so filtering n2-candidates equal to n1 removes
// exactly the self/duplicate contamination -> exact top-2 (bug in r3: self-merge
// inflated k2 to k1, making B ~= global max and killing the fast path).
template<int CTRL>
__device__ __forceinline__ void top2_step(double& k1, double& k2, float& x, float& y, float& z){
  double p1 = dpp_mov_f64<CTRL>(k1);
  double p2 = dpp_mov_f64<CTRL>(k2);
  float qx = dpp_mov_f32<CTRL>(x);
  float qy = dpp_mov_f32<CTRL>(y);
  float qz = dpp_mov_f32<CTRL>(z);
  double n1 = fmax(k1, p1);
  double lo = fmin(k1, p1);
  double c1 = (lo == n1) ? 0.0 : lo;
  double c2 = (k2 == n1) ? 0.0 : k2;
  double c3 = (p2 == n1) ? 0.0 : p2;
  double n2 = fmax(c1, fmax(c2, c3));
  bool s = p1 > k1;
  x = s ? qx : x; y = s ? qy : y; z = s ? qz : z;
  k1 = n1; k2 = n2;
}

// ------- prep+knn mega-kernel: 256 blocks (1/CU), 512 threads (8 waves) ----
// bid 0..7: FPS with candidate caching: each full reduce round publishes
//   per-wave top-2 keys + top-1 coords; the 8 top-1s become candidates with
//   bound B = max(2nd-bests). While max candidate key' >= B, winners are
//   emitted from registers with NO barrier/reduce (exact: keys only shrink,
//   candidate updates replay the identical fp32 sequence -> bit-exact).
// bid 8..255: workers — tx/cvt chores, then pipelined KNN polling fps_idx,
//   with a single packed f64 min-reduce per k (1 barrier instead of 2).
#define PREP_FPS 8
#define PREP_TOTAL 256
#define NWORK 248          // 31 workers per batch

__global__ __launch_bounds__(512) void prep_kernel(
    const float* __restrict__ xyz, const int* __restrict__ far0, int* __restrict__ fps_idx,
    const float* __restrict__ x, short* __restrict__ xT,
    const float* __restrict__ Wproj, const float* __restrict__ Wl1, const float* __restrict__ Wl2,
    const float* __restrict__ Wc1, const float* __restrict__ Wc2,
    const float* __restrict__ Wk, const float* __restrict__ Wv,
    const float* __restrict__ Wq, const float* __restrict__ Wo,
    const float* __restrict__ Wqkv, const float* __restrict__ Wao,
    const float* __restrict__ Wf1, const float* __restrict__ Wf2,
    const float* __restrict__ t_in,
    short* __restrict__ wbf,
    int* __restrict__ knn_idx, float* __restrict__ out0){
  // big smem to keep 1 block/CU scheduling behavior identical to prior rounds
  __shared__ __align__(16) char smemc[57728];
  int bid = blockIdx.x, tid = threadIdx.x;
  if(bid < PREP_FPS){
    int b = bid;
    double* pwave = (double*)smemc;          // [2][8][4]: k1,k2,xy,z_
    const float* xb = xyz + (size_t)b*Nc*3;
    float px[8], py[8], pz[8], dmin[8];
#pragma unroll
    for(int j=0;j<8;j++){
      int n = tid + 512*j;
      const float* p = xb + n*3;
      px[j]=p[0]; py[j]=p[1]; pz[j]=p[2];
      dmin[j]=1e10f;
    }
    int* out = fps_idx + b*Sc;
    int far0idx = far0[b] & (Nc-1);
    float cx = xb[far0idx*3], cy = xb[far0idx*3+1], cz = xb[far0idx*3+2];
    if(tid==0)
      __hip_atomic_store(&out[0], far0idx, __ATOMIC_RELAXED, __HIP_MEMORY_SCOPE_AGENT);
    double cand_key[8]; unsigned cand_lo[8]; float cdx[8], cdy[8], cdz[8];
#pragma unroll
    for(int i=0;i<8;i++){ cand_key[i]=0.0; cand_lo[i]=0u; cdx[i]=0.f; cdy[i]=0.f; cdz[i]=0.f; }
    double B = 1e300;       // invalid until first full round
    int it = 1, fr = 0;
    while(true){
      // 1) apply last emitted center to per-point dmin (exact sequence)
#pragma unroll
      for(int j=0;j<8;j++){
        float dx = __fsub_rn(px[j], cx);
        float dy = __fsub_rn(py[j], cy);
        float dz = __fsub_rn(pz[j], cz);
        float d = __fadd_rn(__fadd_rn(__fmul_rn(dx,dx), __fmul_rn(dy,dy)), __fmul_rn(dz,dz));
        dmin[j] = fminf(dmin[j], d);
      }
      // 2) apply last emitted center to candidate keys (identical fp sequence)
#pragma unroll
      for(int i=0;i<8;i++){
        float dx = __fsub_rn(cdx[i], cx);
        float dy = __fsub_rn(cdy[i], cy);
        float dz = __fsub_rn(cdz[i], cz);
        float d = __fadd_rn(__fadd_rn(__fmul_rn(dx,dx), __fmul_rn(dy,dy)), __fmul_rn(dz,dz));
        cand_key[i] = fmin(cand_key[i], packkey(d, cand_lo[i]));
      }
      // 3) best candidate
      double m = cand_key[0]; int slot = 0;
      float wx = cdx[0], wy = cdy[0], wz = cdz[0];
#pragma unroll
      for(int i=1;i<8;i++){
        bool s = cand_key[i] > m;
        m = s ? cand_key[i] : m; slot = s ? i : slot;
        wx = s ? cdx[i] : wx; wy = s ? cdy[i] : wy; wz = s ? cdz[i] : wz;
      }
      if(m >= B){
        // provably the global argmax: emit without any reduce round
        int idx = (Nc-1) - (int)(unsigned)(__double_as_longlong(m) & 0xFFFFFFFFULL);
        if(tid==0)
          __hip_atomic_store(&out[it], idx, __ATOMIC_RELAXED, __HIP_MEMORY_SCOPE_AGENT);
        cx = wx; cy = wy; cz = wz;
#pragma unroll
        for(int i=0;i<8;i++) if(i==slot) cand_key[i] = 0.0;
        if(++it == Sc) break;
        continue;
      }
      // 4) FULL ROUND: per-wave top-2 (+top-1 coords), publish, block reduce
      double m1, m2; float X, Y, Z;
      {
        m1 = packkey(dmin[0], (unsigned)((Nc-1) - tid));
        m2 = 0.0; X = px[0]; Y = py[0]; Z = pz[0];
#pragma unroll
        for(int j=1;j<8;j++){
          double kj = packkey(dmin[j], (unsigned)((Nc-1) - (tid + 512*j)));
          double lo = fmin(m1, kj);
          m2 = fmax(m2, lo);
          bool s = kj > m1;
          X = s ? px[j] : X; Y = s ? py[j] : Y; Z = s ? pz[j] : Z;
          m1 = fmax(m1, kj);
        }
      }
      top2_step<0x111>(m1,m2,X,Y,Z);
      top2_step<0x112>(m1,m2,X,Y,Z);
      top2_step<0x114>(m1,m2,X,Y,Z);
      top2_step<0x118>(m1,m2,X,Y,Z);
      top2_step<0x142>(m1,m2,X,Y,Z);
      top2_step<0x143>(m1,m2,X,Y,Z);
      double* row = pwave + (fr&1)*32 + (tid>>6)*4;
      if((tid&63)==63){
        row[0]=m1; row[1]=m2; row[2]=pack2f(X,Y); row[3]=pack2f(Z,0.f);
      }
      bar_lds();
      const double* basep = pwave + (fr&1)*32;
      fr++;
      double K[8]; float XX[8], YY[8], ZZ[8]; double Bn = 0.0;
#pragma unroll
      for(int i=0;i<8;i++){
        K[i] = basep[i*4+0];
        Bn = fmax(Bn, basep[i*4+1]);
        long long bxy = __double_as_longlong(basep[i*4+2]);
        XX[i] = __int_as_float((int)(unsigned)(bxy & 0xFFFFFFFFLL));
        YY[i] = __int_as_float((int)(unsigned)((unsigned long long)bxy >> 32));
        ZZ[i] = __int_as_float((int)(unsigned)(__double_as_longlong(basep[i*4+3]) & 0xFFFFFFFFLL));
      }
      double mm = K[0]; int sl = 0; float wx2 = XX[0], wy2 = YY[0], wz2 = ZZ[0];
#pragma unroll
      for(int i=1;i<8;i++){
        bool s = K[i] > mm;
        mm = s ? K[i] : mm; sl = s ? i : sl;
        wx2 = s ? XX[i] : wx2; wy2 = s ? YY[i] : wy2; wz2 = s ? ZZ[i] : wz2;
      }
      B = Bn;
#pragma unroll
      for(int i=0;i<8;i++){
        cand_key[i] = K[i];
        cand_lo[i] = (unsigned)(__double_as_longlong(K[i]) & 0xFFFFFFFFULL);
        cdx[i] = XX[i]; cdy[i] = YY[i]; cdz[i] = ZZ[i];
      }
#pragma unroll
      for(int i=0;i<8;i++) if(i==sl) cand_key[i] = 0.0;
      int idx = (Nc-1) - (int)(unsigned)(__double_as_longlong(mm) & 0xFFFFFFFFULL);
      if(tid==0)
        __hip_atomic_store(&out[it], idx, __ATOMIC_RELAXED, __HIP_MEMORY_SCOPE_AGENT);
      cx = wx2; cy = wy2; cz = wz2;
      if(++it == Sc) break;
    }
  } else {
    int wid = bid - PREP_FPS;       // 0..247
    int b = wid / 31;               // batch of this worker
    int widb = wid % 31;            // worker index within batch
    // ---- chore A: transpose_x tiles, strided over workers ----
    short (*tile)[33] = (short(*)[33])smemc;
    for(int t = wid; t < 4096; t += NWORK){
      int bb = t >> 9;
      int rem = t & 511;
      int n0 = (rem & 127) * 32;
      int c0 = (rem >> 7) * 32;
      int tx = tid & 31, ty = tid >> 5;   // ty 0..15
      __syncthreads();
#pragma unroll
      for(int i=0;i<32;i+=16)
        tile[ty+i][tx] = f2b(x[((size_t)bb*CINc + (c0+ty+i))*Nc + n0+tx]);
      __syncthreads();
#pragma unroll
      for(int i=0;i<32;i+=16)
        xT[((size_t)bb*Nc + (n0+ty+i))*CINc + c0+tx] = tile[tx][ty+i];
    }
    // ---- chore B: weight/t conversion, strided over workers ----
    {
      int gid = wid*512 + tid;
      const int stride = NWORK*512;
      short* p = wbf;
      for(int i=gid; i<COUTc*CINc; i+=stride) p[i] = f2b(Wproj[i]);
      p += COUTc*CINc;
      for(int i=gid; i<COUTc*COUTc; i+=stride) p[i] = f2b(Wl1[i]);
      p += COUTc*COUTc;
      for(int i=gid; i<COUTc*COUTc; i+=stride) p[i] = f2b(Wl2[i]);
      p += COUTc*COUTc;
      for(int i=gid; i<COUTc*COUTc; i+=stride) p[i] = f2b(Wc1[i]);
      p += COUTc*COUTc;
      for(int i=gid; i<COUTc*COUTc; i+=stride) p[i] = f2b(Wc2[i]);
      p += COUTc*COUTc;
      for(int i=gid; i<TCHc*COUTc; i+=stride) p[i] = f2b(Wk[i]);
      p += TCHc*COUTc;
      for(int i=gid; i<TCHc*COUTc; i+=stride) p[i] = f2b(Wv[i]);
      p += TCHc*COUTc;
      for(int i=gid; i<TCHc*TCHc; i+=stride) p[i] = f2b(Wq[i]);
      p += TCHc*TCHc;
      for(int i=gid; i<TCHc*TCHc; i+=stride) p[i] = f2b(Wo[i]);
      p += TCHc*TCHc;
      for(int i=gid; i<3*TCHc*TCHc; i+=stride) p[i] = f2b(Wqkv[i]);
      p += 3*TCHc*TCHc;
      for(int i=gid; i<TCHc*TCHc; i+=stride) p[i] = f2b(Wao[i]);
      p += TCHc*TCHc;
      for(int i=gid; i<2*TCHc*TCHc; i+=stride) p[i] = f2b(Wf1[i]);
      p += 2*TCHc*TCHc;
      for(int i=gid; i<2*TCHc*TCHc; i+=stride) p[i] = f2b(Wf2[i]);
      p += 2*TCHc*TCHc;
      for(int i=gid; i<Bc*Mc*TCHc; i+=stride) p[i] = f2b(t_in[i]);
    }
    // ---- KNN: coords+dd in registers (8/thread); queries gated by polling ----
    int* s_qn = (int*)(smemc + 2112);
    double* pvd = (double*)(smemc + 2176);   // [2][8] parity-buffered partials
    const float* xb = xyz + (size_t)b*Nc*3;
    float px[8], py[8], pz[8], db[8];
#pragma unroll
    for(int j=0;j<8;j++){
      int n = tid + 512*j;
      float xx=xb[n*3], yy=xb[n*3+1], zz=xb[n*3+2];
      px[j]=xx; py[j]=yy; pz[j]=zz;
      db[j] = __fadd_rn(__fadd_rn(__fmul_rn(xx,xx),__fmul_rn(yy,yy)),__fmul_rn(zz,zz));
    }
    __syncthreads();
    for(int s = widb; s < Sc; s += 31){
      if(tid==0){
        int qn;
        for(;;){
          qn = __hip_atomic_load(&fps_idx[b*Sc + s], __ATOMIC_RELAXED, __HIP_MEMORY_SCOPE_AGENT);
          if(qn >= 0) break;
          __builtin_amdgcn_s_sleep(8);
        }
        s_qn[0] = qn & (Nc-1);
      }
      bar_lds();
      int qn = s_qn[0];
      const float* q = xyz + ((size_t)b*Nc + qn)*3;
      float sxq = q[0], syq = q[1], szq = q[2];
      if(tid < 3) out0[((size_t)b*Sc + s)*3 + tid] = q[tid];
      float ss = __fadd_rn(__fadd_rn(__fmul_rn(sxq,sxq),__fmul_rn(syq,syq)),__fmul_rn(szq,szq));
      float dv[8];
#pragma unroll
      for(int j=0;j<8;j++){
        float e = __fmul_rn(sxq,px[j]);
        e = __fadd_rn(e, __fmul_rn(syq,py[j]));
        e = __fadd_rn(e, __fmul_rn(szq,pz[j]));
        dv[j] = __fadd_rn(__fadd_rn(__fmul_rn(-2.f,e), ss), db[j]);
      }
      int* ob = knn_idx + ((size_t)b*Sc + s)*Kc;
      for(int k=0;k<Kc;k++){
        // single packed min-reduce: (dist_bits<<32)|index -> min dist, tie min idx.
        // clamp to >=0 for the PACK only: only the self-point can go negative
        // (fp cancellation), clamping keeps it the minimum and keeps all packed
        // keys positive so f64 ordering == u64 ordering (index tie-break correct).
        double kk = packkey(fmaxf(dv[0],0.f), (unsigned)tid);
#pragma unroll
        for(int j=1;j<8;j++) kk = fmin(kk, packkey(fmaxf(dv[j],0.f), (unsigned)(tid + 512*j)));
        kk = dpp_min_f64<0x111>(kk);
        kk = dpp_min_f64<0x112>(kk);
        kk = dpp_min_f64<0x114>(kk);
        kk = dpp_min_f64<0x118>(kk);
        kk = dpp_min_f64<0x142>(kk);
        kk = dpp_min_f64<0x143>(kk);
        double* pb = pvd + (k&1)*8;
        if((tid&63)==63) pb[tid>>6] = kk;
        bar_lds();
        double w0 = fmin(fmin(fmin(pb[0],pb[1]),fmin(pb[2],pb[3])),
                         fmin(fmin(pb[4],pb[5]),fmin(pb[6],pb[7])));
        int win = (int)(unsigned)(__double_as_longlong(w0) & 0xFFFFFFFFULL);
        if(tid==0) ob[k] = win;
#pragma unroll
        for(int j=0;j<8;j++) if(tid + 512*j == win) dv[j] = 3.4e38f;
      }
    }
  }
}

// ---------------- 128x128 MFMA GEMM, A/W bf16 ------------------------------
template<int HAS_BN, int HAS_GELU, int HAS_RES, typename TRES>
__global__ __launch_bounds__(256) void gemm128(
    const short* __restrict__ A, const short* __restrict__ W,
    const float* __restrict__ g, const float* __restrict__ bias,
    const TRES* __restrict__ Res, short* __restrict__ Out,
    int Nn, int Kk){
  __shared__ short As[128*32];
  __shared__ short Bs[128*32];
  int bm = blockIdx.y*128, bn = blockIdx.x*128;
  int tid = threadIdx.x;
  int wave = tid>>6, lane = tid&63, quad = lane>>4, l16 = lane&15;
  int wr = (wave>>1)*64, wc = (wave&1)*64;
  f32x4 acc[4][4];
#pragma unroll
  for(int i=0;i<4;i++)
#pragma unroll
    for(int j=0;j<4;j++) acc[i][j] = (f32x4){0.f,0.f,0.f,0.f};
  int sr = tid>>2, scc = (tid&3)*8;
  const short* Ap = A + (size_t)(bm+sr)*Kk + scc;
  const short* Wp = W + (size_t)(bn+sr)*Kk + scc;
  for(int k0=0; k0<Kk; k0+=32){
    gl_lds16(Ap + k0,                    As + tid*8);
    gl_lds16(Ap + k0 + (size_t)64*Kk,    As + 2048 + tid*8);
    gl_lds16(Wp + k0,                    Bs + tid*8);
    gl_lds16(Wp + k0 + (size_t)64*Kk,    Bs + 2048 + tid*8);
    __syncthreads();
    bf16x8 af[4], bfr[4];
#pragma unroll
    for(int mt=0; mt<4; mt++) af[mt]  = *(const bf16x8*)&As[(wr+mt*16+l16)*32 + quad*8];
#pragma unroll
    for(int nt=0; nt<4; nt++) bfr[nt] = *(const bf16x8*)&Bs[(wc+nt*16+l16)*32 + quad*8];
#pragma unroll
    for(int mt=0; mt<4; mt++)
#pragma unroll
      for(int nt=0; nt<4; nt++)
        acc[mt][nt] = __builtin_amdgcn_mfma_f32_16x16x32_bf16(af[mt], bfr[nt], acc[mt][nt], 0, 0, 0);
    __syncthreads();
  }
#pragma unroll
  for(int nt=0; nt<4; nt++){
    int col = bn + wc + nt*16 + l16;
    float gs = 0.f, bs_ = 0.f;
    if(HAS_BN){ gs = g[col] * BN_SCALE_F; bs_ = bias[col]; }
#pragma unroll
    for(int mt=0; mt<4; mt++){
#pragma unroll
      for(int r2=0;r2<4;r2++){
        int row = bm + wr + mt*16 + quad*4 + r2;
        float v = acc[mt][nt][r2];
        if(HAS_BN) v = v*gs + bs_;
        if(HAS_RES) v += rdval(Res + (size_t)row*Nn + col);
        if(HAS_GELU) v = gelu_f(v);
        Out[(size_t)row*Nn + col] = f2b(v);
      }
    }
  }
}

// ------- proj 128x128: gathered edge A, W via DMA; rows offset by R0 -------
__global__ __launch_bounds__(256) void proj128(
    const short* __restrict__ xT, const int* __restrict__ knn_idx, const int* __restrict__ fps_idx,
    const short* __restrict__ W, const float* __restrict__ g, const float* __restrict__ bias,
    short* __restrict__ Out, int R0){
  __shared__ short As[128*32];
  __shared__ short Bs[128*32];
  int bm = blockIdx.y*128, bn = blockIdx.x*128;
  int tid = threadIdx.x;
  int wave = tid>>6, lane = tid&63, quad = lane>>4, l16 = lane&15;
  int wr = (wave>>1)*64, wc = (wave&1)*64;
  f32x4 acc[4][4];
#pragma unroll
  for(int i=0;i<4;i++)
#pragma unroll
    for(int j=0;j<4;j++) acc[i][j] = (f32x4){0.f,0.f,0.f,0.f};
  int sr = tid>>2, scc = (tid&3)*8;
  int Rg0 = R0 + bm + sr, Rg1 = Rg0 + 64;
  int b0 = Rg0 / (Sc*Kc), b1 = Rg1 / (Sc*Kc);
  int nk0 = knn_idx[Rg0] & (Nc-1), nk1 = knn_idx[Rg1] & (Nc-1);
  int nc0 = fps_idx[Rg0 / Kc] & (Nc-1), nc1 = fps_idx[Rg1 / Kc] & (Nc-1);
  const short* pk0 = xT + ((size_t)b0*Nc + nk0)*CINc + scc;
  const short* pc0 = xT + ((size_t)b0*Nc + nc0)*CINc + scc;
  const short* pk1 = xT + ((size_t)b1*Nc + nk1)*CINc + scc;
  const short* pc1 = xT + ((size_t)b1*Nc + nc1)*CINc + scc;
  const short* Wp  = W + (size_t)(bn+sr)*CINc + scc;
  for(int k0=0; k0<CINc; k0+=32){
    gl_lds16(Wp + k0,                      Bs + tid*8);
    gl_lds16(Wp + k0 + (size_t)64*CINc,    Bs + 2048 + tid*8);
    bf16x8 vk = *(const bf16x8*)(pk0 + k0);
    bf16x8 vc = *(const bf16x8*)(pc0 + k0);
    bf16x8 e0, e1;
#pragma unroll
    for(int i=0;i<8;i++) e0[i] = f2b(__fsub_rn(b2f(vk[i]), b2f(vc[i])));
    vk = *(const bf16x8*)(pk1 + k0);
    vc = *(const bf16x8*)(pc1 + k0);
#pragma unroll
    for(int i=0;i<8;i++) e1[i] = f2b(__fsub_rn(b2f(vk[i]), b2f(vc[i])));
    *(bf16x8*)&As[tid*8] = e0;
    *(bf16x8*)&As[2048 + tid*8] = e1;
    __syncthreads();
    bf16x8 af[4], bfr[4];
#pragma unroll
    for(int mt=0; mt<4; mt++) af[mt]  = *(const bf16x8*)&As[(wr+mt*16+l16)*32 + quad*8];
#pragma unroll
    for(int nt=0; nt<4; nt++) bfr[nt] = *(const bf16x8*)&Bs[(wc+nt*16+l16)*32 + quad*8];
#pragma unroll
    for(int mt=0; mt<4; mt++)
#pragma unroll
      for(int nt=0; nt<4; nt++)
        acc[mt][nt] = __builtin_amdgcn_mfma_f32_16x16x32_bf16(af[mt], bfr[nt], acc[mt][nt], 0, 0, 0);
    __syncthreads();
  }
#pragma unroll
  for(int nt=0; nt<4; nt++){
    int col = bn + wc + nt*16 + l16;
    float gs = g[col] * BN_SCALE_F, bs_ = bias[col];
#pragma unroll
    for(int mt=0; mt<4; mt++){
#pragma unroll
      for(int r2=0;r2<4;r2++){
        int row = bm + wr + mt*16 + quad*4 + r2;
        float v = acc[mt][nt][r2]*gs + bs_;
        Out[(size_t)row*COUTc + col] = f2b(gelu_f(v));
      }
    }
  }
}

// -- l2 GEMM + residual + gelu + max over k (BM=48), A & W bf16 via DMA -----
__global__ __launch_bounds__(192) void gemm_l2max(
    const short* __restrict__ A, const short* __restrict__ W,
    const float* __restrict__ g, const float* __restrict__ bias,
    const short* __restrict__ Hres, short* __restrict__ Fout, int R0){
  __shared__ short As[48*32];
  __shared__ short Bs[64*32];
  __shared__ float sm[48][65];
  int bm = blockIdx.y*48, bn = blockIdx.x*64;
  int tid = threadIdx.x;
  int wave = tid >> 6, lane = tid & 63, quad = lane >> 4, l16 = lane & 15;
  f32x4 acc[4];
#pragma unroll
  for(int i=0;i<4;i++) acc[i] = (f32x4){0.f,0.f,0.f,0.f};
  const short* Ap  = A + (size_t)(bm + (tid>>2))*COUTc + (tid&3)*8;
  const short* Wp  = W + (size_t)(bn + (tid>>2))*COUTc + (tid&3)*8;
  const short* Wp2 = W + (size_t)(bn + 48 + (lane>>2))*COUTc + (lane&3)*8;
  for(int k0=0; k0<COUTc; k0+=32){
    gl_lds16(Ap + k0, As + tid*8);
    gl_lds16(Wp + k0, Bs + tid*8);
    if(wave==0) gl_lds16(Wp2 + k0, Bs + 1536 + lane*8);
    __syncthreads();
    bf16x8 a = *(const bf16x8*)&As[(wave*16 + l16)*32 + quad*8];
#pragma unroll
    for(int ct=0; ct<4; ct++){
      bf16x8 bb = *(const bf16x8*)&Bs[(ct*16 + l16)*32 + quad*8];
      acc[ct] = __builtin_amdgcn_mfma_f32_16x16x32_bf16(a, bb, acc[ct], 0, 0, 0);
    }
    __syncthreads();
  }
#pragma unroll
  for(int ct=0; ct<4; ct++){
    int col = bn + ct*16 + l16;
    float gs = g[col] * BN_SCALE_F, bs_ = bias[col];
#pragma unroll
    for(int r2=0;r2<4;r2++){
      int rl = wave*16 + quad*4 + r2;
      float v = acc[ct][r2]*gs + bs_;
      v += b2f(Hres[(size_t)(bm+rl)*COUTc + col]);
      sm[rl][ct*16 + l16] = gelu_f(v);
    }
  }
  __syncthreads();
  if(tid < 128){
    int gl = tid >> 6, col = tid & 63;
    float mx = -3.4e38f;
#pragma unroll
    for(int kk=0; kk<Kc; kk++) mx = fmaxf(mx, sm[gl*Kc + kk][col]);
    int gg = R0/Kc + blockIdx.y*2 + gl;   // global (b*Sc+s)
    Fout[(size_t)gg*COUTc + bn + col] = f2b(mx);
  }
}

// ------- 64x64 MFMA GEMM, A & W bf16, both staged via global_load_lds ------
template<int HAS_BN, int HAS_GELU, int HAS_RES, typename TRES, typename TOUT>
__global__ __launch_bounds__(256) void gemm64d(
    const short* __restrict__ A, const short* __restrict__ W,
    const float* __restrict__ g, const float* __restrict__ bias,
    const TRES* __restrict__ Res, TOUT* __restrict__ Out,
    int Nn, int Kk){
  __shared__ short As[64*32];
  __shared__ short Bs[64*32];
  int bm = blockIdx.y*64, bn = blockIdx.x*64;
  int tid = threadIdx.x;
  int wave = tid >> 6, lane = tid & 63, quad = lane >> 4, l16 = lane & 15;
  f32x4 acc[4];
#pragma unroll
  for(int i=0;i<4;i++) acc[i] = (f32x4){0.f,0.f,0.f,0.f};
  const short* Ap = A + (size_t)(bm + (tid>>2))*Kk + (tid&3)*8;
  const short* Wp = W + (size_t)(bn + (tid>>2))*Kk + (tid&3)*8;
  for(int k0=0; k0<Kk; k0+=32){
    gl_lds16(Ap + k0, As + tid*8);
    gl_lds16(Wp + k0, Bs + tid*8);
    __syncthreads();
    bf16x8 a = *(const bf16x8*)&As[(wave*16 + l16)*32 + quad*8];
#pragma unroll
    for(int ct=0; ct<4; ct++){
      bf16x8 bb = *(const bf16x8*)&Bs[(ct*16 + l16)*32 + quad*8];
      acc[ct] = __builtin_amdgcn_mfma_f32_16x16x32_bf16(a, bb, acc[ct], 0, 0, 0);
    }
    __syncthreads();
  }
#pragma unroll
  for(int ct=0; ct<4; ct++){
    int col = bn + ct*16 + l16;
    float gs = 0.f, bs_ = 0.f;
    if(HAS_BN){ gs = g[col] * BN_SCALE_F; bs_ = bias[col]; }
#pragma unroll
    for(int r2=0;r2<4;r2++){
      int row = bm + wave*16 + quad*4 + r2;
      float v = acc[ct][r2];
      if(HAS_BN) v = v*gs + bs_;
      if(HAS_RES) v += rdval(Res + (size_t)row*Nn + col);
      if(HAS_GELU) v = gelu_f(v);
      wrval(Out + (size_t)row*Nn + col, v);
    }
  }
}

// ---------------- f2 [B,S,C] bf16 -> x_out [B,C,S] f32 ---------------------
__global__ __launch_bounds__(256) void transpose_f(const short* __restrict__ f2, float* __restrict__ out1){
  __shared__ short tile[32][33];
  int b = blockIdx.z;
  int s0 = blockIdx.x*32, c0 = blockIdx.y*32;
  int tx = threadIdx.x & 31, ty = threadIdx.x >> 5;
#pragma unroll
  for(int i=0;i<32;i+=8)
    tile[ty+i][tx] = f2[((size_t)b*Sc + (s0+ty+i))*COUTc + c0+tx];
  __syncthreads();
#pragma unroll
  for(int i=0;i<32;i+=8)
    out1[((size_t)b*COUTc + (c0+ty+i))*Sc + s0+tx] = b2f(tile[tx][ty+i]);
}

// ------- Local2Former attention: block per (b,m); kv packed [row,512] ------
__global__ __launch_bounds__(256) void l2f_attn(
    const short* __restrict__ qb, const short* __restrict__ kv,
    short* __restrict__ ao){
  int blk = blockIdx.x; int b = blk / Mc; int m = blk % Mc;
  int tid = threadIdx.x;
  __shared__ float qs[TCHc];
  __shared__ float aw[Sc];
  __shared__ float red[8];
  qs[tid] = b2f(qb[(size_t)(b*Mc+m)*TCHc + tid]);
  __syncthreads();
  float sc[4];
#pragma unroll
  for(int jj=0;jj<4;jj++){
    int j = tid + 256*jj;
    const short* kp = kv + ((size_t)b*Sc + j)*512;
    float a = 0.f;
    for(int c=0;c<TCHc;c+=8){
      bf16x8 v8 = *(const bf16x8*)(kp + c);
#pragma unroll
      for(int i=0;i<8;i++) a += b2f(v8[i]) * qs[c+i];
    }
    sc[jj] = a * 0.0625f;   // TCH^-0.5
  }
  float mx = fmaxf(fmaxf(sc[0],sc[1]), fmaxf(sc[2],sc[3]));
#pragma unroll
  for(int off=32; off>0; off>>=1) mx = fmaxf(mx, __shfl_xor(mx, off));
  if((tid&63)==0) red[tid>>6] = mx;
  __syncthreads();
  mx = fmaxf(fmaxf(red[0],red[1]), fmaxf(red[2],red[3]));
  float se = 0.f;
#pragma unroll
  for(int jj=0;jj<4;jj++){
    float e = expf(sc[jj] - mx);
    aw[tid + 256*jj] = e;
    se += e;
  }
#pragma unroll
  for(int off=32; off>0; off>>=1) se += __shfl_xor(se, off);
  if((tid&63)==0) red[4 + (tid>>6)] = se;
  __syncthreads();
  se = red[4]+red[5]+red[6]+red[7];
  float inv = 1.f/se;
#pragma unroll
  for(int jj=0;jj<4;jj++) aw[tid + 256*jj] *= inv;
  __syncthreads();
  float acc = 0.f;
  const short* vp = kv + (size_t)b*Sc*512 + 256 + tid;
  for(int j=0;j<Sc;j++) acc += aw[j] * b2f(vp[(size_t)j*512]);
  ao[(size_t)(b*Mc+m)*TCHc + tid] = f2b(acc);
}

// ---------------- Former MHA: block per (b,h,m), 64 threads ----------------
__global__ __launch_bounds__(64) void former_attn(const short* __restrict__ qkv, short* __restrict__ oa){
  int blk = blockIdx.x;
  int m = blk % Mc; int bh = blk / Mc; int h = bh % Hc; int b = bh / Hc;
  int lane = threadIdx.x;
  __shared__ float qs[HDc];
  __shared__ float aw2[32];
  const short* base = qkv + (size_t)(b*Mc)*(3*TCHc);
  qs[lane] = b2f(base[(size_t)m*3*TCHc + h*HDc + lane]);
  __syncthreads();
  int j = lane & 31;
  const short* kp = base + (size_t)j*3*TCHc + TCHc + h*HDc;
  float s = 0.f;
  for(int d=0; d<HDc; d+=8){
    bf16x8 v8 = *(const bf16x8*)(kp + d);
#pragma unroll
    for(int i=0;i<8;i++) s += b2f(v8[i]) * qs[d+i];
  }
  s *= 0.125f;  // HD^-0.5
  float mx = s;
#pragma unroll
  for(int off=16; off>0; off>>=1) mx = fmaxf(mx, __shfl_xor(mx, off, 32));
  float e = expf(s - mx);
  float se = e;
#pragma unroll
  for(int off=16; off>0; off>>=1) se += __shfl_xor(se, off, 32);
  if(lane < 32) aw2[lane] = e / se;
  __syncthreads();
  float acc = 0.f;
  const short* vp = base + 2*TCHc + h*HDc + lane;
  for(int jj=0; jj<32; jj++) acc += aw2[jj] * b2f(vp[(size_t)jj*3*TCHc]);
  oa[(size_t)(b*Mc+m)*TCHc + h*HDc + lane] = f2b(acc);
}

// ---------------- LayerNorm over 256: f32 in, bf16 out ---------------------
__global__ __launch_bounds__(64) void ln_kernel(const float* __restrict__ X, const float* __restrict__ g,
                                                const float* __restrict__ bb, short* __restrict__ O){
  int row = blockIdx.x, lane = threadIdx.x;
  const float* xp = X + (size_t)row*TCHc;
  float x[4];
#pragma unroll
  for(int j2=0;j2<4;j2++) x[j2] = xp[lane + 64*j2];
  float sm = x[0]+x[1]+x[2]+x[3];
#pragma unroll
  for(int off=32; off>0; off>>=1) sm += __shfl_xor(sm, off);
  float mu = sm * (1.f/256.f);
  float vs = 0.f;
#pragma unroll
  for(int j2=0;j2<4;j2++){ float d = x[j2]-mu; vs += d*d; }
#pragma unroll
  for(int off=32; off>0; off>>=1) vs += __shfl_xor(vs, off);
  float var = vs * (1.f/256.f);
  float rstd = 1.f / sqrtf(var + 1e-5f);
#pragma unroll
  for(int j2=0;j2<4;j2++){
    int c = lane + 64*j2;
    float o = (x[j2]-mu)*rstd*g[c] + bb[c];
    O[(size_t)row*TCHc + c] = f2b(o);
  }
}

extern "C" void kernel_launch(void* const* d_in, const int* in_sizes, int n_in,
                              void* d_out, int out_size, void* d_ws, size_t ws_size,
                              hipStream_t stream){
  const float* xyz  = (const float*)d_in[0];
  const float* x    = (const float*)d_in[1];
  const float* t_in = (const float*)d_in[2];
  const int*   far0 = (const int*)d_in[3];
  const float* Wproj=(const float*)d_in[4];  const float* gproj=(const float*)d_in[5];  const float* bproj=(const float*)d_in[6];
  const float* Wl1 = (const float*)d_in[7];  const float* gl1 = (const float*)d_in[8];  const float* bl1 = (const float*)d_in[9];
  const float* Wl2 = (const float*)d_in[10]; const float* gl2 = (const float*)d_in[11]; const float* bl2 = (const float*)d_in[12];
  const float* Wc1 = (const float*)d_in[13]; const float* gc1 = (const float*)d_in[14]; const float* bc1 = (const float*)d_in[15];
  const float* Wc2 = (const float*)d_in[16]; const float* gc2 = (const float*)d_in[17]; const float* bc2 = (const float*)d_in[18];
  const float* Wq  = (const float*)d_in[19]; const float* Wk  = (const float*)d_in[20]; const float* Wv  = (const float*)d_in[21];
  const float* Wo  = (const float*)d_in[22];
  const float* ln1g= (const float*)d_in[23]; const float* ln1b= (const float*)d_in[24];
  const float* Wqkv= (const float*)d_in[25]; const float* Wao = (const float*)d_in[26];
  const float* ln2g= (const float*)d_in[27]; const float* ln2b= (const float*)d_in[28];
  const float* Wf1 = (const float*)d_in[29]; const float* Wf2 = (const float*)d_in[30];

  char* wsb = (char*)d_ws;
  size_t off = 0;
  auto alloc = [&](size_t bytes)->void*{ void* p = wsb + off; off += (bytes + 255) & ~(size_t)255; return p; };
  int*   fps_i = (int*)alloc((size_t)Bc*Sc*4);
  int*   knn   = (int*)alloc((size_t)Bc*Sc*Kc*4);
  short* xT    = (short*)alloc((size_t)Bc*Nc*CINc*2);
  // bf16 pool: proj,l1,l2,c1,c2,k,v,q,o,qkv,ao,f1,f2,t
  size_t wbf_elems = (size_t)COUTc*CINc + 4*(size_t)COUTc*COUTc + 2*(size_t)TCHc*COUTc
                   + 2*(size_t)TCHc*TCHc + 3*(size_t)TCHc*TCHc + (size_t)TCHc*TCHc
                   + 2*(size_t)TCHc*TCHc + 2*(size_t)TCHc*TCHc + (size_t)Bc*Mc*TCHc;
  short* wbf   = (short*)alloc(wbf_elems*2);
  short* fbuf  = (short*)alloc((size_t)Bc*Sc*COUTc*2);
  short* rcbuf = (short*)alloc((size_t)Bc*Sc*COUTc*2);
  short* f2buf = (short*)alloc((size_t)Bc*Sc*COUTc*2);
  short* kvbuf = (short*)alloc((size_t)Bc*Sc*512*2);
  short* qbuf  = (short*)alloc((size_t)Bc*Mc*TCHc*2);
  short* a1out = (short*)alloc((size_t)Bc*Mc*TCHc*2);
  float* t1buf = (float*)alloc((size_t)Bc*Mc*TCHc*4);
  short* hnbuf = (short*)alloc((size_t)Bc*Mc*TCHc*2);
  short* qkvb  = (short*)alloc((size_t)Bc*Mc*3*TCHc*2);
  short* a2out = (short*)alloc((size_t)Bc*Mc*TCHc*2);
  float* t2buf = (float*)alloc((size_t)Bc*Mc*TCHc*4);
  short* hn2buf= (short*)alloc((size_t)Bc*Mc*TCHc*2);
  short* g1buf = (short*)alloc((size_t)Bc*Mc*2*TCHc*2);
  size_t full_bytes  = (size_t)Bc*MBAT*COUTc*2;   // ~96 MB
  size_t batch_bytes = (size_t)MBAT*COUTc*2;      // ~12 MB
  bool batched = (off + 2*(full_bytes + 256) <= ws_size);
  short* hbuf = (short*)alloc(batched ? full_bytes : batch_bytes);
  short* rbuf = (short*)alloc(batched ? full_bytes : batch_bytes);
  if(off > ws_size) return;  // insufficient workspace; fail visibly

  short* wproj_bf = wbf;
  short* wl1_bf   = wproj_bf + COUTc*CINc;
  short* wl2_bf   = wl1_bf + COUTc*COUTc;
  short* wc1_bf   = wl2_bf + COUTc*COUTc;
  short* wc2_bf   = wc1_bf + COUTc*COUTc;
  short* wkv_bf   = wc2_bf + COUTc*COUTc;     // [512,256]
  short* wq_bf    = wkv_bf + 2*TCHc*COUTc;
  short* wo_bf    = wq_bf + TCHc*TCHc;
  short* wqkv_bf  = wo_bf + TCHc*TCHc;
  short* wao_bf   = wqkv_bf + 3*TCHc*TCHc;
  short* wf1_bf   = wao_bf + TCHc*TCHc;
  short* wf2_bf   = wf1_bf + 2*TCHc*TCHc;
  short* tbf      = wf2_bf + 2*TCHc*TCHc;     // t_in as bf16

  float* out0 = (float*)d_out;
  float* out1 = out0 + (size_t)Bc*Sc*3;
  float* out2 = out1 + (size_t)Bc*COUTc*Sc;

  // --- prep+knn: fps publishes winners (relaxed); workers poll fps_idx ---
  hipMemsetAsync(fps_i, 0xFF, (size_t)Bc*Sc*4, stream);   // sentinel: -1 = not yet written
  prep_kernel<<<PREP_TOTAL, 512, 0, stream>>>(xyz, far0, fps_i, x, xT,
                                              Wproj, Wl1, Wl2, Wc1, Wc2, Wk, Wv,
                                              Wq, Wo, Wqkv, Wao, Wf1, Wf2, t_in,
                                              wbf, knn, out0);
  // --- Local (round-10 proven config) ---
  if(batched){
    proj128<<<dim3(COUTc/128, (Bc*MBAT)/128), 256, 0, stream>>>(xT, knn, fps_i, wproj_bf, gproj, bproj, hbuf, 0);
    gemm128<1,1,0,short><<<dim3(COUTc/128, (Bc*MBAT)/128), 256, 0, stream>>>(hbuf, wl1_bf, gl1, bl1, (const short*)nullptr, rbuf, COUTc, COUTc);
    gemm_l2max<<<dim3(COUTc/64, (Bc*MBAT)/48), 192, 0, stream>>>(rbuf, wl2_bf, gl2, bl2, hbuf, fbuf, 0);
  } else {
    for(int b=0; b<Bc; b++){
      proj128<<<dim3(COUTc/128, MBAT/128), 256, 0, stream>>>(xT, knn, fps_i, wproj_bf, gproj, bproj, hbuf, b*MBAT);
      gemm128<1,1,0,short><<<dim3(COUTc/128, MBAT/128), 256, 0, stream>>>(hbuf, wl1_bf, gl1, bl1, (const short*)nullptr, rbuf, COUTc, COUTc);
      gemm_l2max<<<dim3(COUTc/64, MBAT/48), 192, 0, stream>>>(rbuf, wl2_bf, gl2, bl2, hbuf, fbuf, b*MBAT);
    }
  }
  // --- Channel ---
  gemm64d<1,1,0,short,short><<<dim3(COUTc/64, (Bc*Sc)/64), 256, 0, stream>>>(fbuf, wc1_bf, gc1, bc1, (const short*)nullptr, rcbuf, COUTc, COUTc);
  gemm64d<1,1,1,short,short><<<dim3(COUTc/64, (Bc*Sc)/64), 256, 0, stream>>>(rcbuf, wc2_bf, gc2, bc2, fbuf, f2buf, COUTc, COUTc);
  transpose_f<<<dim3(Sc/32, COUTc/32, Bc), 256, 0, stream>>>(f2buf, out1);
  // --- Local2Former ---
  gemm64d<0,0,0,short,short><<<dim3(TCHc/64, (Bc*Mc)/64), 256, 0, stream>>>(tbf, wq_bf, nullptr, nullptr, (const short*)nullptr, qbuf, TCHc, TCHc);
  gemm64d<0,0,0,short,short><<<dim3(512/64, (Bc*Sc)/64), 256, 0, stream>>>(f2buf, wkv_bf, nullptr, nullptr, (const short*)nullptr, kvbuf, 512, COUTc);
  l2f_attn<<<Bc*Mc, 256, 0, stream>>>(qbuf, kvbuf, a1out);
  gemm64d<0,0,1,float,float><<<dim3(TCHc/64, (Bc*Mc)/64), 256, 0, stream>>>(a1out, wo_bf, nullptr, nullptr, t_in, t1buf, TCHc, TCHc);
  // --- Former ---
  ln_kernel<<<Bc*Mc, 64, 0, stream>>>(t1buf, ln1g, ln1b, hnbuf);
  gemm64d<0,0,0,short,short><<<dim3((3*TCHc)/64, (Bc*Mc)/64), 256, 0, stream>>>(hnbuf, wqkv_bf, nullptr, nullptr, (const short*)nullptr, qkvb, 3*TCHc, TCHc);
  former_attn<<<Bc*Hc*Mc, 64, 0, stream>>>(qkvb, a2out);
  gemm64d<0,0,1,float,float><<<dim3(TCHc/64, (Bc*Mc)/64), 256, 0, stream>>>(a2out, wao_bf, nullptr, nullptr, t1buf, t2buf, TCHc, TCHc);
  ln_kernel<<<Bc*Mc, 64, 0, stream>>>(t2buf, ln2g, ln2b, hn2buf);
  gemm64d<0,1,0,short,short><<<dim3((2*TCHc)/64, (Bc*Mc)/64), 256, 0, stream>>>(hn2buf, wf1_bf, nullptr, nullptr, (const short*)nullptr, g1buf, 2*TCHc, TCHc);
  gemm64d<0,0,1,float,float><<<dim3(TCHc/64, (Bc*Mc)/64), 256, 0, stream>>>(g1buf, wf2_bf, nullptr, nullptr, t2buf, out2, TCHc, 2*TCHc);
}

// Round 5
// 1257.490 us; speedup vs baseline: 1.2937x; 1.2937x over previous
//
#include <hip/hip_runtime.h>
#include <math.h>

#define Bc 8
#define Nc 4096
#define CINc 128
#define COUTc 256
#define Sc 1024
#define Kc 24
#define TCHc 256
#define Mc 32
#define Hc 4
#define HDc 64
#define MBAT (Sc*Kc)      // rows per batch in Local stage: 24576

#define BN_SCALE_F 0.9999950000374997f

typedef __attribute__((ext_vector_type(8))) short bf16x8;
typedef __attribute__((ext_vector_type(4))) float f32x4;
typedef __attribute__((ext_vector_type(2))) float f32x2;

__device__ __forceinline__ float b2f(short s){
  unsigned int u = ((unsigned int)(unsigned short)s) << 16;
  union { unsigned int u; float f; } c; c.u = u; return c.f;
}
__device__ __forceinline__ short f2b(float f){
  union { unsigned int u; float f; } c; c.f = f;
  unsigned int u = c.u;
  unsigned int r = (u + 0x7fffu + ((u >> 16) & 1u)) >> 16;
  return (short)(r & 0xffffu);
}
__device__ __forceinline__ float gelu_f(float v){
  return 0.5f * v * (1.f + erff(v * 0.7071067811865475f));
}
__device__ __forceinline__ float rdval(const float* p){ return *p; }
__device__ __forceinline__ float rdval(const short* p){ return b2f(*p); }
__device__ __forceinline__ void wrval(float* p, float v){ *p = v; }
__device__ __forceinline__ void wrval(short* p, float v){ *p = f2b(v); }

// async global->LDS, 16B per lane (dest follows lane order: base + lane*16B)
__device__ __forceinline__ void gl_lds16(const short* g, short* l){
  __builtin_amdgcn_global_load_lds(
     (const __attribute__((address_space(1))) void*)g,
     (__attribute__((address_space(3))) void*)l, 16, 0, 0);
}

// barrier that drains ONLY LDS ops (lgkmcnt), leaving global stores in flight.
__device__ __forceinline__ void bar_lds(){
  asm volatile("s_waitcnt lgkmcnt(0)" ::: "memory");
  __builtin_amdgcn_s_barrier();
}

// packed fp32 (VOP3P): 2 IEEE f32 ops per instruction, identical rounding to
// the scalar sequence. gfx950 keeps full-rate packed f32 (157 TF peak = packed).
__device__ __forceinline__ f32x2 pk_add(f32x2 a, f32x2 b){
  f32x2 d; asm("v_pk_add_f32 %0, %1, %2" : "=v"(d) : "v"(a), "v"(b)); return d;
}
__device__ __forceinline__ f32x2 pk_mul(f32x2 a, f32x2 b){
  f32x2 d; asm("v_pk_mul_f32 %0, %1, %2" : "=v"(d) : "v"(a), "v"(b)); return d;
}

// ---- packed-key helper: (f32 bits << 32) | tag  as positive f64 -----------
__device__ __forceinline__ double packkey(float d, unsigned tag){
  return __longlong_as_double((long long)(
    (((unsigned long long)(unsigned)__float_as_int(d)) << 32) | (unsigned long long)tag));
}

template<int CTRL>
__device__ __forceinline__ double dpp_mov_f64(double v){
  long long x = __double_as_longlong(v);
  int lo = (int)(unsigned)(x & 0xFFFFFFFFLL);
  int hi = (int)(unsigned)((unsigned long long)x >> 32);
  int plo = __builtin_amdgcn_update_dpp(lo, lo, CTRL, 0xF, 0xF, false);
  int phi = __builtin_amdgcn_update_dpp(hi, hi, CTRL, 0xF, 0xF, false);
  return __longlong_as_double((long long)(((unsigned long long)(unsigned)phi << 32)
                                          | (unsigned)plo));
}
template<int CTRL>
__device__ __forceinline__ double dpp_min_f64(double v){
  return fmin(v, dpp_mov_f64<CTRL>(v));
}
template<int CTRL>
__device__ __forceinline__ float dpp_max_f32(float v){
  int p = __builtin_amdgcn_update_dpp(__float_as_int(v), __float_as_int(v), CTRL, 0xF, 0xF, false);
  return fmaxf(v, __int_as_float(p));
}

// ------- prep+knn mega-kernel: 256 blocks (1/CU), 512 threads (8 waves) ----
// bid 0..7: FPS, plain full rounds (rounds 2/4 proved pruning/speculation do
//   not pay). Lean iteration: packed-f32 distance updates + f32 DPP max ladder
//   with exact argmax-first tie-break (lane owns 8 CONSECUTIVE points so lane
//   order == global index order; ballot+ffs -> first tied lane; in-lane lowest
//   tied element; cross-wave via packed f64 keys). Winner published via
//   relaxed agent atomic into fps_idx.
// bid 8..255: workers — tx/cvt chores, then pipelined KNN polling fps_idx,
//   single packed f64 min-reduce per k (1 barrier per k).
#define PREP_FPS 8
#define PREP_TOTAL 256
#define NWORK 248          // 31 workers per batch

__global__ __launch_bounds__(512) void prep_kernel(
    const float* __restrict__ xyz, const int* __restrict__ far0, int* __restrict__ fps_idx,
    const float* __restrict__ x, short* __restrict__ xT,
    const float* __restrict__ Wproj, const float* __restrict__ Wl1, const float* __restrict__ Wl2,
    const float* __restrict__ Wc1, const float* __restrict__ Wc2,
    const float* __restrict__ Wk, const float* __restrict__ Wv,
    const float* __restrict__ Wq, const float* __restrict__ Wo,
    const float* __restrict__ Wqkv, const float* __restrict__ Wao,
    const float* __restrict__ Wf1, const float* __restrict__ Wf2,
    const float* __restrict__ t_in,
    short* __restrict__ wbf,
    int* __restrict__ knn_idx, float* __restrict__ out0){
  // layout: sx/sy/sz f32[4096] @0 (49152B) | pwave f64[16] @49152 (128B)
  __shared__ __align__(16) char smemc[57728];
  int bid = blockIdx.x, tid = threadIdx.x;
  if(bid < PREP_FPS){
    int b = bid;
    float* sx = (float*)smemc;
    float* sy = sx + Nc;
    float* sz = sy + Nc;
    double* pwave = (double*)(smemc + 49152);   // [2][8]
    const float* xb = xyz + (size_t)b*Nc*3;
    for(int i=tid; i<Nc; i+=512){
      const float* p = xb + i*3;
      sx[i]=p[0]; sy[i]=p[1]; sz[i]=p[2];
    }
    __syncthreads();
    int lane = tid & 63, wv = tid >> 6;
    int base = wv*512 + lane*8;     // lane owns 8 CONSECUTIVE global indices
    f32x2 px2[4], py2[4], pz2[4];
    float dmn[8];
#pragma unroll
    for(int i=0;i<4;i++){
      px2[i] = (f32x2){ sx[base+2*i], sx[base+2*i+1] };
      py2[i] = (f32x2){ sy[base+2*i], sy[base+2*i+1] };
      pz2[i] = (f32x2){ sz[base+2*i], sz[base+2*i+1] };
      dmn[2*i] = 1e10f; dmn[2*i+1] = 1e10f;
    }
    int winner = far0[b] & (Nc-1);
    int* out = fps_idx + b*Sc;
    for(int it=0; it<Sc; it++){
      if(tid==0)
        __hip_atomic_store(&out[it], winner, __ATOMIC_RELAXED, __HIP_MEMORY_SCOPE_AGENT);
      float cx=sx[winner], cy=sy[winner], cz=sz[winner];
      f32x2 ncx = (f32x2){-cx,-cx}, ncy = (f32x2){-cy,-cy}, ncz = (f32x2){-cz,-cz};
      float vmax = -1.f;
#pragma unroll
      for(int i=0;i<4;i++){
        // exact: x + (-c) == x - c ; ((dx2+dy2)+dz2) association preserved
        f32x2 dx = pk_add(px2[i], ncx);
        f32x2 dy = pk_add(py2[i], ncy);
        f32x2 dz = pk_add(pz2[i], ncz);
        f32x2 d  = pk_add(pk_add(pk_mul(dx,dx), pk_mul(dy,dy)), pk_mul(dz,dz));
        dmn[2*i]   = fminf(dmn[2*i],   d[0]);
        dmn[2*i+1] = fminf(dmn[2*i+1], d[1]);
        vmax = fmaxf(vmax, fmaxf(dmn[2*i], dmn[2*i+1]));
      }
      // wave max (f32) -> lane 63, broadcast via readlane
      float wm = vmax;
      wm = dpp_max_f32<0x111>(wm);
      wm = dpp_max_f32<0x112>(wm);
      wm = dpp_max_f32<0x114>(wm);
      wm = dpp_max_f32<0x118>(wm);
      wm = dpp_max_f32<0x142>(wm);
      wm = dpp_max_f32<0x143>(wm);
      float smax = __int_as_float(__builtin_amdgcn_readlane(__float_as_int(wm), 63));
      // exact argmax-first tie-break: lowest tied element in this lane
      int lj = 0;
#pragma unroll
      for(int j=7;j>=0;j--) if(dmn[j]==smax) lj = j;
      unsigned long long mk = __ballot(vmax == smax);
      int flane = __ffsll(mk) - 1;            // first lane holding the max
      int ljw = __builtin_amdgcn_readlane(lj, flane);
      int widx = wv*512 + flane*8 + ljw;      // wave's argmax (global index)
      if(lane==0)
        pwave[(it&1)*8 + wv] = packkey(smax, (unsigned)((Nc-1) - widx));
      bar_lds();
      const double* pb = pwave + (it&1)*8;
      double kb = fmax(fmax(fmax(pb[0],pb[1]), fmax(pb[2],pb[3])),
                       fmax(fmax(pb[4],pb[5]), fmax(pb[6],pb[7])));
      winner = (Nc-1) - (int)(unsigned)(__double_as_longlong(kb) & 0xFFFFFFFFULL);
    }
  } else {
    int wid = bid - PREP_FPS;       // 0..247
    int b = wid / 31;               // batch of this worker
    int widb = wid % 31;            // worker index within batch
    // ---- chore A: transpose_x tiles, strided over workers ----
    short (*tile)[33] = (short(*)[33])smemc;
    for(int t = wid; t < 4096; t += NWORK){
      int bb = t >> 9;
      int rem = t & 511;
      int n0 = (rem & 127) * 32;
      int c0 = (rem >> 7) * 32;
      int tx = tid & 31, ty = tid >> 5;   // ty 0..15
      __syncthreads();
#pragma unroll
      for(int i=0;i<32;i+=16)
        tile[ty+i][tx] = f2b(x[((size_t)bb*CINc + (c0+ty+i))*Nc + n0+tx]);
      __syncthreads();
#pragma unroll
      for(int i=0;i<32;i+=16)
        xT[((size_t)bb*Nc + (n0+ty+i))*CINc + c0+tx] = tile[tx][ty+i];
    }
    // ---- chore B: weight/t conversion, strided over workers ----
    {
      int gid = wid*512 + tid;
      const int stride = NWORK*512;
      short* p = wbf;
      for(int i=gid; i<COUTc*CINc; i+=stride) p[i] = f2b(Wproj[i]);
      p += COUTc*CINc;
      for(int i=gid; i<COUTc*COUTc; i+=stride) p[i] = f2b(Wl1[i]);
      p += COUTc*COUTc;
      for(int i=gid; i<COUTc*COUTc; i+=stride) p[i] = f2b(Wl2[i]);
      p += COUTc*COUTc;
      for(int i=gid; i<COUTc*COUTc; i+=stride) p[i] = f2b(Wc1[i]);
      p += COUTc*COUTc;
      for(int i=gid; i<COUTc*COUTc; i+=stride) p[i] = f2b(Wc2[i]);
      p += COUTc*COUTc;
      for(int i=gid; i<TCHc*COUTc; i+=stride) p[i] = f2b(Wk[i]);
      p += TCHc*COUTc;
      for(int i=gid; i<TCHc*COUTc; i+=stride) p[i] = f2b(Wv[i]);
      p += TCHc*COUTc;
      for(int i=gid; i<TCHc*TCHc; i+=stride) p[i] = f2b(Wq[i]);
      p += TCHc*TCHc;
      for(int i=gid; i<TCHc*TCHc; i+=stride) p[i] = f2b(Wo[i]);
      p += TCHc*TCHc;
      for(int i=gid; i<3*TCHc*TCHc; i+=stride) p[i] = f2b(Wqkv[i]);
      p += 3*TCHc*TCHc;
      for(int i=gid; i<TCHc*TCHc; i+=stride) p[i] = f2b(Wao[i]);
      p += TCHc*TCHc;
      for(int i=gid; i<2*TCHc*TCHc; i+=stride) p[i] = f2b(Wf1[i]);
      p += 2*TCHc*TCHc;
      for(int i=gid; i<2*TCHc*TCHc; i+=stride) p[i] = f2b(Wf2[i]);
      p += 2*TCHc*TCHc;
      for(int i=gid; i<Bc*Mc*TCHc; i+=stride) p[i] = f2b(t_in[i]);
    }
    // ---- KNN: coords+dd in registers (8/thread); queries gated by polling ----
    int* s_qn = (int*)(smemc + 2112);
    double* pvd = (double*)(smemc + 2176);   // [2][8] parity-buffered partials
    const float* xb = xyz + (size_t)b*Nc*3;
    float px[8], py[8], pz[8], db[8];
#pragma unroll
    for(int j=0;j<8;j++){
      int n = tid + 512*j;
      float xx=xb[n*3], yy=xb[n*3+1], zz=xb[n*3+2];
      px[j]=xx; py[j]=yy; pz[j]=zz;
      db[j] = __fadd_rn(__fadd_rn(__fmul_rn(xx,xx),__fmul_rn(yy,yy)),__fmul_rn(zz,zz));
    }
    __syncthreads();
    for(int s = widb; s < Sc; s += 31){
      if(tid==0){
        int qn;
        for(;;){
          qn = __hip_atomic_load(&fps_idx[b*Sc + s], __ATOMIC_RELAXED, __HIP_MEMORY_SCOPE_AGENT);
          if(qn >= 0) break;
          __builtin_amdgcn_s_sleep(8);
        }
        s_qn[0] = qn & (Nc-1);
      }
      bar_lds();
      int qn = s_qn[0];
      const float* q = xyz + ((size_t)b*Nc + qn)*3;
      float sxq = q[0], syq = q[1], szq = q[2];
      if(tid < 3) out0[((size_t)b*Sc + s)*3 + tid] = q[tid];
      float ss = __fadd_rn(__fadd_rn(__fmul_rn(sxq,sxq),__fmul_rn(syq,syq)),__fmul_rn(szq,szq));
      float dv[8];
#pragma unroll
      for(int j=0;j<8;j++){
        float e = __fmul_rn(sxq,px[j]);
        e = __fadd_rn(e, __fmul_rn(syq,py[j]));
        e = __fadd_rn(e, __fmul_rn(szq,pz[j]));
        dv[j] = __fadd_rn(__fadd_rn(__fmul_rn(-2.f,e), ss), db[j]);
      }
      int* ob = knn_idx + ((size_t)b*Sc + s)*Kc;
      for(int k=0;k<Kc;k++){
        // single packed min-reduce: (dist_bits<<32)|index -> min dist, tie min idx.
        // clamp to >=0 for the PACK only: only the self-point can go negative
        // (fp cancellation); clamping keeps it the minimum and keeps all packed
        // keys positive so f64 ordering == u64 ordering (index tie-break correct).
        double kk = packkey(fmaxf(dv[0],0.f), (unsigned)tid);
#pragma unroll
        for(int j=1;j<8;j++) kk = fmin(kk, packkey(fmaxf(dv[j],0.f), (unsigned)(tid + 512*j)));
        kk = dpp_min_f64<0x111>(kk);
        kk = dpp_min_f64<0x112>(kk);
        kk = dpp_min_f64<0x114>(kk);
        kk = dpp_min_f64<0x118>(kk);
        kk = dpp_min_f64<0x142>(kk);
        kk = dpp_min_f64<0x143>(kk);
        double* pb = pvd + (k&1)*8;
        if((tid&63)==63) pb[tid>>6] = kk;
        bar_lds();
        double w0 = fmin(fmin(fmin(pb[0],pb[1]),fmin(pb[2],pb[3])),
                         fmin(fmin(pb[4],pb[5]),fmin(pb[6],pb[7])));
        int win = (int)(unsigned)(__double_as_longlong(w0) & 0xFFFFFFFFULL);
        if(tid==0) ob[k] = win;
#pragma unroll
        for(int j=0;j<8;j++) if(tid + 512*j == win) dv[j] = 3.4e38f;
      }
    }
  }
}

// ---------------- 128x128 MFMA GEMM, A/W bf16 ------------------------------
template<int HAS_BN, int HAS_GELU, int HAS_RES, typename TRES>
__global__ __launch_bounds__(256) void gemm128(
    const short* __restrict__ A, const short* __restrict__ W,
    const float* __restrict__ g, const float* __restrict__ bias,
    const TRES* __restrict__ Res, short* __restrict__ Out,
    int Nn, int Kk){
  __shared__ short As[128*32];
  __shared__ short Bs[128*32];
  int bm = blockIdx.y*128, bn = blockIdx.x*128;
  int tid = threadIdx.x;
  int wave = tid>>6, lane = tid&63, quad = lane>>4, l16 = lane&15;
  int wr = (wave>>1)*64, wc = (wave&1)*64;
  f32x4 acc[4][4];
#pragma unroll
  for(int i=0;i<4;i++)
#pragma unroll
    for(int j=0;j<4;j++) acc[i][j] = (f32x4){0.f,0.f,0.f,0.f};
  int sr = tid>>2, scc = (tid&3)*8;
  const short* Ap = A + (size_t)(bm+sr)*Kk + scc;
  const short* Wp = W + (size_t)(bn+sr)*Kk + scc;
  for(int k0=0; k0<Kk; k0+=32){
    gl_lds16(Ap + k0,                    As + tid*8);
    gl_lds16(Ap + k0 + (size_t)64*Kk,    As + 2048 + tid*8);
    gl_lds16(Wp + k0,                    Bs + tid*8);
    gl_lds16(Wp + k0 + (size_t)64*Kk,    Bs + 2048 + tid*8);
    __syncthreads();
    bf16x8 af[4], bfr[4];
#pragma unroll
    for(int mt=0; mt<4; mt++) af[mt]  = *(const bf16x8*)&As[(wr+mt*16+l16)*32 + quad*8];
#pragma unroll
    for(int nt=0; nt<4; nt++) bfr[nt] = *(const bf16x8*)&Bs[(wc+nt*16+l16)*32 + quad*8];
#pragma unroll
    for(int mt=0; mt<4; mt++)
#pragma unroll
      for(int nt=0; nt<4; nt++)
        acc[mt][nt] = __builtin_amdgcn_mfma_f32_16x16x32_bf16(af[mt], bfr[nt], acc[mt][nt], 0, 0, 0);
    __syncthreads();
  }
#pragma unroll
  for(int nt=0; nt<4; nt++){
    int col = bn + wc + nt*16 + l16;
    float gs = 0.f, bs_ = 0.f;
    if(HAS_BN){ gs = g[col] * BN_SCALE_F; bs_ = bias[col]; }
#pragma unroll
    for(int mt=0; mt<4; mt++){
#pragma unroll
      for(int r2=0;r2<4;r2++){
        int row = bm + wr + mt*16 + quad*4 + r2;
        float v = acc[mt][nt][r2];
        if(HAS_BN) v = v*gs + bs_;
        if(HAS_RES) v += rdval(Res + (size_t)row*Nn + col);
        if(HAS_GELU) v = gelu_f(v);
        Out[(size_t)row*Nn + col] = f2b(v);
      }
    }
  }
}

// ------- proj 128x128: gathered edge A, W via DMA; rows offset by R0 -------
__global__ __launch_bounds__(256) void proj128(
    const short* __restrict__ xT, const int* __restrict__ knn_idx, const int* __restrict__ fps_idx,
    const short* __restrict__ W, const float* __restrict__ g, const float* __restrict__ bias,
    short* __restrict__ Out, int R0){
  __shared__ short As[128*32];
  __shared__ short Bs[128*32];
  int bm = blockIdx.y*128, bn = blockIdx.x*128;
  int tid = threadIdx.x;
  int wave = tid>>6, lane = tid&63, quad = lane>>4, l16 = lane&15;
  int wr = (wave>>1)*64, wc = (wave&1)*64;
  f32x4 acc[4][4];
#pragma unroll
  for(int i=0;i<4;i++)
#pragma unroll
    for(int j=0;j<4;j++) acc[i][j] = (f32x4){0.f,0.f,0.f,0.f};
  int sr = tid>>2, scc = (tid&3)*8;
  int Rg0 = R0 + bm + sr, Rg1 = Rg0 + 64;
  int b0 = Rg0 / (Sc*Kc), b1 = Rg1 / (Sc*Kc);
  int nk0 = knn_idx[Rg0] & (Nc-1), nk1 = knn_idx[Rg1] & (Nc-1);
  int nc0 = fps_idx[Rg0 / Kc] & (Nc-1), nc1 = fps_idx[Rg1 / Kc] & (Nc-1);
  const short* pk0 = xT + ((size_t)b0*Nc + nk0)*CINc + scc;
  const short* pc0 = xT + ((size_t)b0*Nc + nc0)*CINc + scc;
  const short* pk1 = xT + ((size_t)b1*Nc + nk1)*CINc + scc;
  const short* pc1 = xT + ((size_t)b1*Nc + nc1)*CINc + scc;
  const short* Wp  = W + (size_t)(bn+sr)*CINc + scc;
  for(int k0=0; k0<CINc; k0+=32){
    gl_lds16(Wp + k0,                      Bs + tid*8);
    gl_lds16(Wp + k0 + (size_t)64*CINc,    Bs + 2048 + tid*8);
    bf16x8 vk = *(const bf16x8*)(pk0 + k0);
    bf16x8 vc = *(const bf16x8*)(pc0 + k0);
    bf16x8 e0, e1;
#pragma unroll
    for(int i=0;i<8;i++) e0[i] = f2b(__fsub_rn(b2f(vk[i]), b2f(vc[i])));
    vk = *(const bf16x8*)(pk1 + k0);
    vc = *(const bf16x8*)(pc1 + k0);
#pragma unroll
    for(int i=0;i<8;i++) e1[i] = f2b(__fsub_rn(b2f(vk[i]), b2f(vc[i])));
    *(bf16x8*)&As[tid*8] = e0;
    *(bf16x8*)&As[2048 + tid*8] = e1;
    __syncthreads();
    bf16x8 af[4], bfr[4];
#pragma unroll
    for(int mt=0; mt<4; mt++) af[mt]  = *(const bf16x8*)&As[(wr+mt*16+l16)*32 + quad*8];
#pragma unroll
    for(int nt=0; nt<4; nt++) bfr[nt] = *(const bf16x8*)&Bs[(wc+nt*16+l16)*32 + quad*8];
#pragma unroll
    for(int mt=0; mt<4; mt++)
#pragma unroll
      for(int nt=0; nt<4; nt++)
        acc[mt][nt] = __builtin_amdgcn_mfma_f32_16x16x32_bf16(af[mt], bfr[nt], acc[mt][nt], 0, 0, 0);
    __syncthreads();
  }
#pragma unroll
  for(int nt=0; nt<4; nt++){
    int col = bn + wc + nt*16 + l16;
    float gs = g[col] * BN_SCALE_F, bs_ = bias[col];
#pragma unroll
    for(int mt=0; mt<4; mt++){
#pragma unroll
      for(int r2=0;r2<4;r2++){
        int row = bm + wr + mt*16 + quad*4 + r2;
        float v = acc[mt][nt][r2]*gs + bs_;
        Out[(size_t)row*COUTc + col] = f2b(gelu_f(v));
      }
    }
  }
}

// -- l2 GEMM + residual + gelu + max over k (BM=48), A & W bf16 via DMA -----
__global__ __launch_bounds__(192) void gemm_l2max(
    const short* __restrict__ A, const short* __restrict__ W,
    const float* __restrict__ g, const float* __restrict__ bias,
    const short* __restrict__ Hres, short* __restrict__ Fout, int R0){
  __shared__ short As[48*32];
  __shared__ short Bs[64*32];
  __shared__ float sm[48][65];
  int bm = blockIdx.y*48, bn = blockIdx.x*64;
  int tid = threadIdx.x;
  int wave = tid >> 6, lane = tid & 63, quad = lane >> 4, l16 = lane & 15;
  f32x4 acc[4];
#pragma unroll
  for(int i=0;i<4;i++) acc[i] = (f32x4){0.f,0.f,0.f,0.f};
  const short* Ap  = A + (size_t)(bm + (tid>>2))*COUTc + (tid&3)*8;
  const short* Wp  = W + (size_t)(bn + (tid>>2))*COUTc + (tid&3)*8;
  const short* Wp2 = W + (size_t)(bn + 48 + (lane>>2))*COUTc + (lane&3)*8;
  for(int k0=0; k0<COUTc; k0+=32){
    gl_lds16(Ap + k0, As + tid*8);
    gl_lds16(Wp + k0, Bs + tid*8);
    if(wave==0) gl_lds16(Wp2 + k0, Bs + 1536 + lane*8);
    __syncthreads();
    bf16x8 a = *(const bf16x8*)&As[(wave*16 + l16)*32 + quad*8];
#pragma unroll
    for(int ct=0; ct<4; ct++){
      bf16x8 bb = *(const bf16x8*)&Bs[(ct*16 + l16)*32 + quad*8];
      acc[ct] = __builtin_amdgcn_mfma_f32_16x16x32_bf16(a, bb, acc[ct], 0, 0, 0);
    }
    __syncthreads();
  }
#pragma unroll
  for(int ct=0; ct<4; ct++){
    int col = bn + ct*16 + l16;
    float gs = g[col] * BN_SCALE_F, bs_ = bias[col];
#pragma unroll
    for(int r2=0;r2<4;r2++){
      int rl = wave*16 + quad*4 + r2;
      float v = acc[ct][r2]*gs + bs_;
      v += b2f(Hres[(size_t)(bm+rl)*COUTc + col]);
      sm[rl][ct*16 + l16] = gelu_f(v);
    }
  }
  __syncthreads();
  if(tid < 128){
    int gl = tid >> 6, col = tid & 63;
    float mx = -3.4e38f;
#pragma unroll
    for(int kk=0; kk<Kc; kk++) mx = fmaxf(mx, sm[gl*Kc + kk][col]);
    int gg = R0/Kc + blockIdx.y*2 + gl;   // global (b*Sc+s)
    Fout[(size_t)gg*COUTc + bn + col] = f2b(mx);
  }
}

// ------- 64x64 MFMA GEMM, A & W bf16, both staged via global_load_lds ------
template<int HAS_BN, int HAS_GELU, int HAS_RES, typename TRES, typename TOUT>
__global__ __launch_bounds__(256) void gemm64d(
    const short* __restrict__ A, const short* __restrict__ W,
    const float* __restrict__ g, const float* __restrict__ bias,
    const TRES* __restrict__ Res, TOUT* __restrict__ Out,
    int Nn, int Kk){
  __shared__ short As[64*32];
  __shared__ short Bs[64*32];
  int bm = blockIdx.y*64, bn = blockIdx.x*64;
  int tid = threadIdx.x;
  int wave = tid >> 6, lane = tid & 63, quad = lane >> 4, l16 = lane & 15;
  f32x4 acc[4];
#pragma unroll
  for(int i=0;i<4;i++) acc[i] = (f32x4){0.f,0.f,0.f,0.f};
  const short* Ap = A + (size_t)(bm + (tid>>2))*Kk + (tid&3)*8;
  const short* Wp = W + (size_t)(bn + (tid>>2))*Kk + (tid&3)*8;
  for(int k0=0; k0<Kk; k0+=32){
    gl_lds16(Ap + k0, As + tid*8);
    gl_lds16(Wp + k0, Bs + tid*8);
    __syncthreads();
    bf16x8 a = *(const bf16x8*)&As[(wave*16 + l16)*32 + quad*8];
#pragma unroll
    for(int ct=0; ct<4; ct++){
      bf16x8 bb = *(const bf16x8*)&Bs[(ct*16 + l16)*32 + quad*8];
      acc[ct] = __builtin_amdgcn_mfma_f32_16x16x32_bf16(a, bb, acc[ct], 0, 0, 0);
    }
    __syncthreads();
  }
#pragma unroll
  for(int ct=0; ct<4; ct++){
    int col = bn + ct*16 + l16;
    float gs = 0.f, bs_ = 0.f;
    if(HAS_BN){ gs = g[col] * BN_SCALE_F; bs_ = bias[col]; }
#pragma unroll
    for(int r2=0;r2<4;r2++){
      int row = bm + wave*16 + quad*4 + r2;
      float v = acc[ct][r2];
      if(HAS_BN) v = v*gs + bs_;
      if(HAS_RES) v += rdval(Res + (size_t)row*Nn + col);
      if(HAS_GELU) v = gelu_f(v);
      wrval(Out + (size_t)row*Nn + col, v);
    }
  }
}

// ---------------- f2 [B,S,C] bf16 -> x_out [B,C,S] f32 ---------------------
__global__ __launch_bounds__(256) void transpose_f(const short* __restrict__ f2, float* __restrict__ out1){
  __shared__ short tile[32][33];
  int b = blockIdx.z;
  int s0 = blockIdx.x*32, c0 = blockIdx.y*32;
  int tx = threadIdx.x & 31, ty = threadIdx.x >> 5;
#pragma unroll
  for(int i=0;i<32;i+=8)
    tile[ty+i][tx] = f2[((size_t)b*Sc + (s0+ty+i))*COUTc + c0+tx];
  __syncthreads();
#pragma unroll
  for(int i=0;i<32;i+=8)
    out1[((size_t)b*COUTc + (c0+ty+i))*Sc + s0+tx] = b2f(tile[tx][ty+i]);
}

// ------- Local2Former attention: block per (b,m); kv packed [row,512] ------
__global__ __launch_bounds__(256) void l2f_attn(
    const short* __restrict__ qb, const short* __restrict__ kv,
    short* __restrict__ ao){
  int blk = blockIdx.x; int b = blk / Mc; int m = blk % Mc;
  int tid = threadIdx.x;
  __shared__ float qs[TCHc];
  __shared__ float aw[Sc];
  __shared__ float red[8];
  qs[tid] = b2f(qb[(size_t)(b*Mc+m)*TCHc + tid]);
  __syncthreads();
  float sc[4];
#pragma unroll
  for(int jj=0;jj<4;jj++){
    int j = tid + 256*jj;
    const short* kp = kv + ((size_t)b*Sc + j)*512;
    float a = 0.f;
    for(int c=0;c<TCHc;c+=8){
      bf16x8 v8 = *(const bf16x8*)(kp + c);
#pragma unroll
      for(int i=0;i<8;i++) a += b2f(v8[i]) * qs[c+i];
    }
    sc[jj] = a * 0.0625f;   // TCH^-0.5
  }
  float mx = fmaxf(fmaxf(sc[0],sc[1]), fmaxf(sc[2],sc[3]));
#pragma unroll
  for(int off=32; off>0; off>>=1) mx = fmaxf(mx, __shfl_xor(mx, off));
  if((tid&63)==0) red[tid>>6] = mx;
  __syncthreads();
  mx = fmaxf(fmaxf(red[0],red[1]), fmaxf(red[2],red[3]));
  float se = 0.f;
#pragma unroll
  for(int jj=0;jj<4;jj++){
    float e = expf(sc[jj] - mx);
    aw[tid + 256*jj] = e;
    se += e;
  }
#pragma unroll
  for(int off=32; off>0; off>>=1) se += __shfl_xor(se, off);
  if((tid&63)==0) red[4 + (tid>>6)] = se;
  __syncthreads();
  se = red[4]+red[5]+red[6]+red[7];
  float inv = 1.f/se;
#pragma unroll
  for(int jj=0;jj<4;jj++) aw[tid + 256*jj] *= inv;
  __syncthreads();
  float acc = 0.f;
  const short* vp = kv + (size_t)b*Sc*512 + 256 + tid;
  for(int j=0;j<Sc;j++) acc += aw[j] * b2f(vp[(size_t)j*512]);
  ao[(size_t)(b*Mc+m)*TCHc + tid] = f2b(acc);
}

// ---------------- Former MHA: block per (b,h,m), 64 threads ----------------
__global__ __launch_bounds__(64) void former_attn(const short* __restrict__ qkv, short* __restrict__ oa){
  int blk = blockIdx.x;
  int m = blk % Mc; int bh = blk / Mc; int h = bh % Hc; int b = bh / Hc;
  int lane = threadIdx.x;
  __shared__ float qs[HDc];
  __shared__ float aw2[32];
  const short* base = qkv + (size_t)(b*Mc)*(3*TCHc);
  qs[lane] = b2f(base[(size_t)m*3*TCHc + h*HDc + lane]);
  __syncthreads();
  int j = lane & 31;
  const short* kp = base + (size_t)j*3*TCHc + TCHc + h*HDc;
  float s = 0.f;
  for(int d=0; d<HDc; d+=8){
    bf16x8 v8 = *(const bf16x8*)(kp + d);
#pragma unroll
    for(int i=0;i<8;i++) s += b2f(v8[i]) * qs[d+i];
  }
  s *= 0.125f;  // HD^-0.5
  float mx = s;
#pragma unroll
  for(int off=16; off>0; off>>=1) mx = fmaxf(mx, __shfl_xor(mx, off, 32));
  float e = expf(s - mx);
  float se = e;
#pragma unroll
  for(int off=16; off>0; off>>=1) se += __shfl_xor(se, off, 32);
  if(lane < 32) aw2[lane] = e / se;
  __syncthreads();
  float acc = 0.f;
  const short* vp = base + 2*TCHc + h*HDc + lane;
  for(int jj=0; jj<32; jj++) acc += aw2[jj] * b2f(vp[(size_t)jj*3*TCHc]);
  oa[(size_t)(b*Mc+m)*TCHc + h*HDc + lane] = f2b(acc);
}

// ---------------- LayerNorm over 256: f32 in, bf16 out ---------------------
__global__ __launch_bounds__(64) void ln_kernel(const float* __restrict__ X, const float* __restrict__ g,
                                                const float* __restrict__ bb, short* __restrict__ O){
  int row = blockIdx.x, lane = threadIdx.x;
  const float* xp = X + (size_t)row*TCHc;
  float x[4];
#pragma unroll
  for(int j2=0;j2<4;j2++) x[j2] = xp[lane + 64*j2];
  float sm = x[0]+x[1]+x[2]+x[3];
#pragma unroll
  for(int off=32; off>0; off>>=1) sm += __shfl_xor(sm, off);
  float mu = sm * (1.f/256.f);
  float vs = 0.f;
#pragma unroll
  for(int j2=0;j2<4;j2++){ float d = x[j2]-mu; vs += d*d; }
#pragma unroll
  for(int off=32; off>0; off>>=1) vs += __shfl_xor(vs, off);
  float var = vs * (1.f/256.f);
  float rstd = 1.f / sqrtf(var + 1e-5f);
#pragma unroll
  for(int j2=0;j2<4;j2++){
    int c = lane + 64*j2;
    float o = (x[j2]-mu)*rstd*g[c] + bb[c];
    O[(size_t)row*TCHc + c] = f2b(o);
  }
}

extern "C" void kernel_launch(void* const* d_in, const int* in_sizes, int n_in,
                              void* d_out, int out_size, void* d_ws, size_t ws_size,
                              hipStream_t stream){
  const float* xyz  = (const float*)d_in[0];
  const float* x    = (const float*)d_in[1];
  const float* t_in = (const float*)d_in[2];
  const int*   far0 = (const int*)d_in[3];
  const float* Wproj=(const float*)d_in[4];  const float* gproj=(const float*)d_in[5];  const float* bproj=(const float*)d_in[6];
  const float* Wl1 = (const float*)d_in[7];  const float* gl1 = (const float*)d_in[8];  const float* bl1 = (const float*)d_in[9];
  const float* Wl2 = (const float*)d_in[10]; const float* gl2 = (const float*)d_in[11]; const float* bl2 = (const float*)d_in[12];
  const float* Wc1 = (const float*)d_in[13]; const float* gc1 = (const float*)d_in[14]; const float* bc1 = (const float*)d_in[15];
  const float* Wc2 = (const float*)d_in[16]; const float* gc2 = (const float*)d_in[17]; const float* bc2 = (const float*)d_in[18];
  const float* Wq  = (const float*)d_in[19]; const float* Wk  = (const float*)d_in[20]; const float* Wv  = (const float*)d_in[21];
  const float* Wo  = (const float*)d_in[22];
  const float* ln1g= (const float*)d_in[23]; const float* ln1b= (const float*)d_in[24];
  const float* Wqkv= (const float*)d_in[25]; const float* Wao = (const float*)d_in[26];
  const float* ln2g= (const float*)d_in[27]; const float* ln2b= (const float*)d_in[28];
  const float* Wf1 = (const float*)d_in[29]; const float* Wf2 = (const float*)d_in[30];

  char* wsb = (char*)d_ws;
  size_t off = 0;
  auto alloc = [&](size_t bytes)->void*{ void* p = wsb + off; off += (bytes + 255) & ~(size_t)255; return p; };
  int*   fps_i = (int*)alloc((size_t)Bc*Sc*4);
  int*   knn   = (int*)alloc((size_t)Bc*Sc*Kc*4);
  short* xT    = (short*)alloc((size_t)Bc*Nc*CINc*2);
  // bf16 pool: proj,l1,l2,c1,c2,k,v,q,o,qkv,ao,f1,f2,t
  size_t wbf_elems = (size_t)COUTc*CINc + 4*(size_t)COUTc*COUTc + 2*(size_t)TCHc*COUTc
                   + 2*(size_t)TCHc*TCHc + 3*(size_t)TCHc*TCHc + (size_t)TCHc*TCHc
                   + 2*(size_t)TCHc*TCHc + 2*(size_t)TCHc*TCHc + (size_t)Bc*Mc*TCHc;
  short* wbf   = (short*)alloc(wbf_elems*2);
  short* fbuf  = (short*)alloc((size_t)Bc*Sc*COUTc*2);
  short* rcbuf = (short*)alloc((size_t)Bc*Sc*COUTc*2);
  short* f2buf = (short*)alloc((size_t)Bc*Sc*COUTc*2);
  short* kvbuf = (short*)alloc((size_t)Bc*Sc*512*2);
  short* qbuf  = (short*)alloc((size_t)Bc*Mc*TCHc*2);
  short* a1out = (short*)alloc((size_t)Bc*Mc*TCHc*2);
  float* t1buf = (float*)alloc((size_t)Bc*Mc*TCHc*4);
  short* hnbuf = (short*)alloc((size_t)Bc*Mc*TCHc*2);
  short* qkvb  = (short*)alloc((size_t)Bc*Mc*3*TCHc*2);
  short* a2out = (short*)alloc((size_t)Bc*Mc*TCHc*2);
  float* t2buf = (float*)alloc((size_t)Bc*Mc*TCHc*4);
  short* hn2buf= (short*)alloc((size_t)Bc*Mc*TCHc*2);
  short* g1buf = (short*)alloc((size_t)Bc*Mc*2*TCHc*2);
  size_t full_bytes  = (size_t)Bc*MBAT*COUTc*2;   // ~96 MB
  size_t batch_bytes = (size_t)MBAT*COUTc*2;      // ~12 MB
  bool batched = (off + 2*(full_bytes + 256) <= ws_size);
  short* hbuf = (short*)alloc(batched ? full_bytes : batch_bytes);
  short* rbuf = (short*)alloc(batched ? full_bytes : batch_bytes);
  if(off > ws_size) return;  // insufficient workspace; fail visibly

  short* wproj_bf = wbf;
  short* wl1_bf   = wproj_bf + COUTc*CINc;
  short* wl2_bf   = wl1_bf + COUTc*COUTc;
  short* wc1_bf   = wl2_bf + COUTc*COUTc;
  short* wc2_bf   = wc1_bf + COUTc*COUTc;
  short* wkv_bf   = wc2_bf + COUTc*COUTc;     // [512,256]
  short* wq_bf    = wkv_bf + 2*TCHc*COUTc;
  short* wo_bf    = wq_bf + TCHc*TCHc;
  short* wqkv_bf  = wo_bf + TCHc*TCHc;
  short* wao_bf   = wqkv_bf + 3*TCHc*TCHc;
  short* wf1_bf   = wao_bf + TCHc*TCHc;
  short* wf2_bf   = wf1_bf + 2*TCHc*TCHc;
  short* tbf      = wf2_bf + 2*TCHc*TCHc;     // t_in as bf16

  float* out0 = (float*)d_out;
  float* out1 = out0 + (size_t)Bc*Sc*3;
  float* out2 = out1 + (size_t)Bc*COUTc*Sc;

  // --- prep+knn: fps publishes winners (relaxed); workers poll fps_idx ---
  hipMemsetAsync(fps_i, 0xFF, (size_t)Bc*Sc*4, stream);   // sentinel: -1 = not yet written
  prep_kernel<<<PREP_TOTAL, 512, 0, stream>>>(xyz, far0, fps_i, x, xT,
                                              Wproj, Wl1, Wl2, Wc1, Wc2, Wk, Wv,
                                              Wq, Wo, Wqkv, Wao, Wf1, Wf2, t_in,
                                              wbf, knn, out0);
  // --- Local (round-10 proven config) ---
  if(batched){
    proj128<<<dim3(COUTc/128, (Bc*MBAT)/128), 256, 0, stream>>>(xT, knn, fps_i, wproj_bf, gproj, bproj, hbuf, 0);
    gemm128<1,1,0,short><<<dim3(COUTc/128, (Bc*MBAT)/128), 256, 0, stream>>>(hbuf, wl1_bf, gl1, bl1, (const short*)nullptr, rbuf, COUTc, COUTc);
    gemm_l2max<<<dim3(COUTc/64, (Bc*MBAT)/48), 192, 0, stream>>>(rbuf, wl2_bf, gl2, bl2, hbuf, fbuf, 0);
  } else {
    for(int b=0; b<Bc; b++){
      proj128<<<dim3(COUTc/128, MBAT/128), 256, 0, stream>>>(xT, knn, fps_i, wproj_bf, gproj, bproj, hbuf, b*MBAT);
      gemm128<1,1,0,short><<<dim3(COUTc/128, MBAT/128), 256, 0, stream>>>(hbuf, wl1_bf, gl1, bl1, (const short*)nullptr, rbuf, COUTc, COUTc);
      gemm_l2max<<<dim3(COUTc/64, MBAT/48), 192, 0, stream>>>(rbuf, wl2_bf, gl2, bl2, hbuf, fbuf, b*MBAT);
    }
  }
  // --- Channel ---
  gemm64d<1,1,0,short,short><<<dim3(COUTc/64, (Bc*Sc)/64), 256, 0, stream>>>(fbuf, wc1_bf, gc1, bc1, (const short*)nullptr, rcbuf, COUTc, COUTc);
  gemm64d<1,1,1,short,short><<<dim3(COUTc/64, (Bc*Sc)/64), 256, 0, stream>>>(rcbuf, wc2_bf, gc2, bc2, fbuf, f2buf, COUTc, COUTc);
  transpose_f<<<dim3(Sc/32, COUTc/32, Bc), 256, 0, stream>>>(f2buf, out1);
  // --- Local2Former ---
  gemm64d<0,0,0,short,short><<<dim3(TCHc/64, (Bc*Mc)/64), 256, 0, stream>>>(tbf, wq_bf, nullptr, nullptr, (const short*)nullptr, qbuf, TCHc, TCHc);
  gemm64d<0,0,0,short,short><<<dim3(512/64, (Bc*Sc)/64), 256, 0, stream>>>(f2buf, wkv_bf, nullptr, nullptr, (const short*)nullptr, kvbuf, 512, COUTc);
  l2f_attn<<<Bc*Mc, 256, 0, stream>>>(qbuf, kvbuf, a1out);
  gemm64d<0,0,1,float,float><<<dim3(TCHc/64, (Bc*Mc)/64), 256, 0, stream>>>(a1out, wo_bf, nullptr, nullptr, t_in, t1buf, TCHc, TCHc);
  // --- Former ---
  ln_kernel<<<Bc*Mc, 64, 0, stream>>>(t1buf, ln1g, ln1b, hnbuf);
  gemm64d<0,0,0,short,short><<<dim3((3*TCHc)/64, (Bc*Mc)/64), 256, 0, stream>>>(hnbuf, wqkv_bf, nullptr, nullptr, (const short*)nullptr, qkvb, 3*TCHc, TCHc);
  former_attn<<<Bc*Hc*Mc, 64, 0, stream>>>(qkvb, a2out);
  gemm64d<0,0,1,float,float><<<dim3(TCHc/64, (Bc*Mc)/64), 256, 0, stream>>>(a2out, wao_bf, nullptr, nullptr, t1buf, t2buf, TCHc, TCHc);
  ln_kernel<<<Bc*Mc, 64, 0, stream>>>(t2buf, ln2g, ln2b, hn2buf);
  gemm64d<0,1,0,short,short><<<dim3((2*TCHc)/64, (Bc*Mc)/64), 256, 0, stream>>>(hn2buf, wf1_bf, nullptr, nullptr, (const short*)nullptr, g1buf, 2*TCHc, TCHc);
  gemm64d<0,0,1,float,float><<<dim3(TCHc/64, (Bc*Mc)/64), 256, 0, stream>>>(g1buf, wf2_bf, nullptr, nullptr, t2buf, out2, TCHc, 2*TCHc);
}

// Round 6
// 1214.590 us; speedup vs baseline: 1.3394x; 1.0353x over previous
//
#include <hip/hip_runtime.h>
#include <math.h>

#define Bc 8
#define Nc 4096
#define CINc 128
#define COUTc 256
#define Sc 1024
#define Kc 24
#define TCHc 256
#define Mc 32
#define Hc 4
#define HDc 64
#define MBAT (Sc*Kc)      // rows per batch in Local stage: 24576

#define BN_SCALE_F 0.9999950000374997f

typedef __attribute__((ext_vector_type(8))) short bf16x8;
typedef __attribute__((ext_vector_type(4))) float f32x4;
typedef __attribute__((ext_vector_type(2))) float f32x2;

__device__ __forceinline__ float b2f(short s){
  unsigned int u = ((unsigned int)(unsigned short)s) << 16;
  union { unsigned int u; float f; } c; c.u = u; return c.f;
}
__device__ __forceinline__ short f2b(float f){
  union { unsigned int u; float f; } c; c.f = f;
  unsigned int u = c.u;
  unsigned int r = (u + 0x7fffu + ((u >> 16) & 1u)) >> 16;
  return (short)(r & 0xffffu);
}
__device__ __forceinline__ float gelu_f(float v){
  return 0.5f * v * (1.f + erff(v * 0.7071067811865475f));
}
__device__ __forceinline__ float rdval(const float* p){ return *p; }
__device__ __forceinline__ float rdval(const short* p){ return b2f(*p); }
__device__ __forceinline__ void wrval(float* p, float v){ *p = v; }
__device__ __forceinline__ void wrval(short* p, float v){ *p = f2b(v); }

// async global->LDS, 16B per lane (dest follows lane order: base + lane*16B)
__device__ __forceinline__ void gl_lds16(const short* g, short* l){
  __builtin_amdgcn_global_load_lds(
     (const __attribute__((address_space(1))) void*)g,
     (__attribute__((address_space(3))) void*)l, 16, 0, 0);
}

// barrier that drains ONLY LDS ops (lgkmcnt), leaving global stores in flight.
__device__ __forceinline__ void bar_lds(){
  asm volatile("s_waitcnt lgkmcnt(0)" ::: "memory");
  __builtin_amdgcn_s_barrier();
}

// packed fp32 (VOP3P): 2 IEEE f32 ops per instruction, identical rounding to
// the scalar sequence (proven exact on HW in round 5: passed absmax check).
__device__ __forceinline__ f32x2 pk_add(f32x2 a, f32x2 b){
  f32x2 d; asm("v_pk_add_f32 %0, %1, %2" : "=v"(d) : "v"(a), "v"(b)); return d;
}
__device__ __forceinline__ f32x2 pk_mul(f32x2 a, f32x2 b){
  f32x2 d; asm("v_pk_mul_f32 %0, %1, %2" : "=v"(d) : "v"(a), "v"(b)); return d;
}

// ---- packed-key helper: (f32 bits << 32) | tag  as positive f64 -----------
__device__ __forceinline__ double packkey(float d, unsigned tag){
  return __longlong_as_double((long long)(
    (((unsigned long long)(unsigned)__float_as_int(d)) << 32) | (unsigned long long)tag));
}

template<int CTRL>
__device__ __forceinline__ double dpp_mov_f64(double v){
  long long x = __double_as_longlong(v);
  int lo = (int)(unsigned)(x & 0xFFFFFFFFLL);
  int hi = (int)(unsigned)((unsigned long long)x >> 32);
  int plo = __builtin_amdgcn_update_dpp(lo, lo, CTRL, 0xF, 0xF, false);
  int phi = __builtin_amdgcn_update_dpp(hi, hi, CTRL, 0xF, 0xF, false);
  return __longlong_as_double((long long)(((unsigned long long)(unsigned)phi << 32)
                                          | (unsigned)plo));
}
template<int CTRL>
__device__ __forceinline__ double dpp_min_f64(double v){
  return fmin(v, dpp_mov_f64<CTRL>(v));
}
template<int CTRL>
__device__ __forceinline__ double dpp_max_f64(double v){
  return fmax(v, dpp_mov_f64<CTRL>(v));
}
__device__ __forceinline__ double readlane_f64(double v, int l){
  long long x = __double_as_longlong(v);
  int lo = __builtin_amdgcn_readlane((int)(unsigned)(x & 0xFFFFFFFFLL), l);
  int hi = __builtin_amdgcn_readlane((int)(unsigned)((unsigned long long)x >> 32), l);
  return __longlong_as_double((long long)(((unsigned long long)(unsigned)hi << 32) | (unsigned)lo));
}

// ------- prep+knn mega-kernel: 256 blocks (1/CU), 512 threads (8 waves) ----
// bid 0..7: FPS with verified double-emit: each round computes the EXACT
//   top-2 keys (packed f64, unique index tags). Emit idx1; then if
//   pack(d(idx2,idx1)^2, tag2) >= K2, idx2's key is unchanged by the new
//   center while all other keys stay strictly below K2 (keys only shrink,
//   K2 is the strict global 2nd) -> idx2 is provably the next winner: emit
//   it too, and the next update applies both centers in one pass
//   (fmin(fmin(dmin,d1),d2) == two sequential updates, bit-exact).
//   No cross-round speculative state (round-4 lesson).
// bid 8..255: workers — tx/cvt chores, then pipelined KNN polling fps_idx,
//   single packed f64 min-reduce per k (1 barrier per k).
#define PREP_FPS 8
#define PREP_TOTAL 256
#define NWORK 248          // 31 workers per batch

__global__ __launch_bounds__(512) void prep_kernel(
    const float* __restrict__ xyz, const int* __restrict__ far0, int* __restrict__ fps_idx,
    const float* __restrict__ x, short* __restrict__ xT,
    const float* __restrict__ Wproj, const float* __restrict__ Wl1, const float* __restrict__ Wl2,
    const float* __restrict__ Wc1, const float* __restrict__ Wc2,
    const float* __restrict__ Wk, const float* __restrict__ Wv,
    const float* __restrict__ Wq, const float* __restrict__ Wo,
    const float* __restrict__ Wqkv, const float* __restrict__ Wao,
    const float* __restrict__ Wf1, const float* __restrict__ Wf2,
    const float* __restrict__ t_in,
    short* __restrict__ wbf,
    int* __restrict__ knn_idx, float* __restrict__ out0){
  // layout: sx/sy/sz f32[4096] @0 (49152B) | pw f64[2][8][2] @49152 (256B)
  __shared__ __align__(16) char smemc[57728];
  int bid = blockIdx.x, tid = threadIdx.x;
  if(bid < PREP_FPS){
    int b = bid;
    float* sx = (float*)smemc;
    float* sy = sx + Nc;
    float* sz = sy + Nc;
    double* pw = (double*)(smemc + 49152);   // [2][8][2]: (k1,k2) per wave
    const float* xb = xyz + (size_t)b*Nc*3;
    for(int i=tid; i<Nc; i+=512){
      const float* p = xb + i*3;
      sx[i]=p[0]; sy[i]=p[1]; sz[i]=p[2];
    }
    __syncthreads();
    int lane = tid & 63, wv = tid >> 6;
    int base = wv*512 + lane*8;     // lane owns 8 CONSECUTIVE global indices
    f32x2 px2[4], py2[4], pz2[4];
    float dmn[8]; unsigned lokey[8];
#pragma unroll
    for(int i=0;i<4;i++){
      px2[i] = (f32x2){ sx[base+2*i], sx[base+2*i+1] };
      py2[i] = (f32x2){ sy[base+2*i], sy[base+2*i+1] };
      pz2[i] = (f32x2){ sz[base+2*i], sz[base+2*i+1] };
      dmn[2*i] = 1e10f; dmn[2*i+1] = 1e10f;
      lokey[2*i]   = (unsigned)((Nc-1) - (base+2*i));
      lokey[2*i+1] = (unsigned)((Nc-1) - (base+2*i+1));
    }
    int* out = fps_idx + b*Sc;
    int w0 = far0[b] & (Nc-1);
    if(tid==0)
      __hip_atomic_store(&out[0], w0, __ATOMIC_RELAXED, __HIP_MEMORY_SCOPE_AGENT);
    float c1x = sx[w0], c1y = sy[w0], c1z = sz[w0];
    float c2x = 0.f, c2y = 0.f, c2z = 0.f;
    bool two = false;
    int it = 1, fr = 0;
    while(it < Sc){
      // ---- update dmin with pending center(s); block-uniform branch ----
      if(two){
        f32x2 n1x={-c1x,-c1x}, n1y={-c1y,-c1y}, n1z={-c1z,-c1z};
        f32x2 n2x={-c2x,-c2x}, n2y={-c2y,-c2y}, n2z={-c2z,-c2z};
#pragma unroll
        for(int i=0;i<4;i++){
          f32x2 dx=pk_add(px2[i],n1x), dy=pk_add(py2[i],n1y), dz=pk_add(pz2[i],n1z);
          f32x2 d1=pk_add(pk_add(pk_mul(dx,dx),pk_mul(dy,dy)),pk_mul(dz,dz));
          f32x2 ex=pk_add(px2[i],n2x), ey=pk_add(py2[i],n2y), ez=pk_add(pz2[i],n2z);
          f32x2 d2=pk_add(pk_add(pk_mul(ex,ex),pk_mul(ey,ey)),pk_mul(ez,ez));
          dmn[2*i]   = fminf(fminf(dmn[2*i],   d1[0]), d2[0]);
          dmn[2*i+1] = fminf(fminf(dmn[2*i+1], d1[1]), d2[1]);
        }
      } else {
        f32x2 n1x={-c1x,-c1x}, n1y={-c1y,-c1y}, n1z={-c1z,-c1z};
#pragma unroll
        for(int i=0;i<4;i++){
          f32x2 dx=pk_add(px2[i],n1x), dy=pk_add(py2[i],n1y), dz=pk_add(pz2[i],n1z);
          f32x2 d1=pk_add(pk_add(pk_mul(dx,dx),pk_mul(dy,dy)),pk_mul(dz,dz));
          dmn[2*i]   = fminf(dmn[2*i],   d1[0]);
          dmn[2*i+1] = fminf(dmn[2*i+1], d1[1]);
        }
      }
      // ---- in-lane exact top-2 over 8 unique keys (merge tree) ----
      double kk0=packkey(dmn[0],lokey[0]), kk1=packkey(dmn[1],lokey[1]);
      double kk2=packkey(dmn[2],lokey[2]), kk3=packkey(dmn[3],lokey[3]);
      double kk4=packkey(dmn[4],lokey[4]), kk5=packkey(dmn[5],lokey[5]);
      double kk6=packkey(dmn[6],lokey[6]), kk7=packkey(dmn[7],lokey[7]);
      double h0=fmax(kk0,kk1), l0=fmin(kk0,kk1);
      double h1=fmax(kk2,kk3), l1=fmin(kk2,kk3);
      double h2=fmax(kk4,kk5), l2=fmin(kk4,kk5);
      double h3=fmax(kk6,kk7), l3=fmin(kk6,kk7);
      double m1a=fmax(h0,h1), m2a=fmax(fmin(h0,h1), (h0>h1)?l0:l1);
      double m1b=fmax(h2,h3), m2b=fmax(fmin(h2,h3), (h2>h3)?l2:l3);
      double w1=fmax(m1a,m1b), w2=fmax(fmin(m1a,m1b), (m1a>m1b)?m2a:m2b);
      // ---- wave top-1 ladder (self-merge-safe), then masked 2nd ladder ----
      double kw = w1;
      kw = dpp_max_f64<0x111>(kw);
      kw = dpp_max_f64<0x112>(kw);
      kw = dpp_max_f64<0x114>(kw);
      kw = dpp_max_f64<0x118>(kw);
      kw = dpp_max_f64<0x142>(kw);
      kw = dpp_max_f64<0x143>(kw);
      double K1w = readlane_f64(kw, 63);
      double km = (w1 == K1w) ? w2 : w1;   // unique keys: exactly one lane swaps
      km = dpp_max_f64<0x111>(km);
      km = dpp_max_f64<0x112>(km);
      km = dpp_max_f64<0x114>(km);
      km = dpp_max_f64<0x118>(km);
      km = dpp_max_f64<0x142>(km);
      km = dpp_max_f64<0x143>(km);
      int p = fr & 1;
      if(lane==63){
        double* row = pw + p*16 + wv*2;
        row[0] = kw;    // wave max
        row[1] = km;    // wave second
      }
      bar_lds();
      fr++;
      const double* q = pw + p*16;
      double q10=q[0], q20=q[1], q11=q[2], q21=q[3], q12=q[4], q22=q[5], q13=q[6], q23=q[7],
             q14=q[8], q24=q[9], q15=q[10], q25=q[11], q16=q[12], q26=q[13], q17=q[14], q27=q[15];
      double g1 = fmax(fmax(fmax(q10,q11),fmax(q12,q13)),fmax(fmax(q14,q15),fmax(q16,q17)));
      // global 2nd = max over { masked k1s, winning wave's k2 }
      double a0=(q10==g1)?q20:q10, a1=(q11==g1)?q21:q11;
      double a2=(q12==g1)?q22:q12, a3=(q13==g1)?q23:q13;
      double a4=(q14==g1)?q24:q14, a5=(q15==g1)?q25:q15;
      double a6=(q16==g1)?q26:q16, a7=(q17==g1)?q27:q17;
      double g2 = fmax(fmax(fmax(a0,a1),fmax(a2,a3)),fmax(fmax(a4,a5),fmax(a6,a7)));
      int idx1 = (Nc-1) - (int)(unsigned)(__double_as_longlong(g1) & 0xFFFFFFFFULL);
      int idx2 = (Nc-1) - (int)(unsigned)(__double_as_longlong(g2) & 0xFFFFFFFFULL);
      if(tid==0)
        __hip_atomic_store(&out[it], idx1, __ATOMIC_RELAXED, __HIP_MEMORY_SCOPE_AGENT);
      it++;
      float nx=sx[idx1], ny=sy[idx1], nz=sz[idx1];
      float rx=sx[idx2], ry=sy[idx2], rz=sz[idx2];
      c1x=nx; c1y=ny; c1z=nz;
      // ---- verify: does idx2 survive the idx1 update as strict argmax? ----
      float ddx=__fsub_rn(rx,nx), ddy=__fsub_rn(ry,ny), ddz=__fsub_rn(rz,nz);
      float dd=__fadd_rn(__fadd_rn(__fmul_rn(ddx,ddx),__fmul_rn(ddy,ddy)),__fmul_rn(ddz,ddz));
      unsigned tag2 = (unsigned)(__double_as_longlong(g2) & 0xFFFFFFFFULL);
      double vk = packkey(dd, tag2);
      if(it < Sc && vk >= g2){
        if(tid==0)
          __hip_atomic_store(&out[it], idx2, __ATOMIC_RELAXED, __HIP_MEMORY_SCOPE_AGENT);
        it++;
        two = true; c2x=rx; c2y=ry; c2z=rz;
      } else {
        two = false;
      }
    }
  } else {
    int wid = bid - PREP_FPS;       // 0..247
    int b = wid / 31;               // batch of this worker
    int widb = wid % 31;            // worker index within batch
    // ---- chore A: transpose_x tiles, strided over workers ----
    short (*tile)[33] = (short(*)[33])smemc;
    for(int t = wid; t < 4096; t += NWORK){
      int bb = t >> 9;
      int rem = t & 511;
      int n0 = (rem & 127) * 32;
      int c0 = (rem >> 7) * 32;
      int tx = tid & 31, ty = tid >> 5;   // ty 0..15
      __syncthreads();
#pragma unroll
      for(int i=0;i<32;i+=16)
        tile[ty+i][tx] = f2b(x[((size_t)bb*CINc + (c0+ty+i))*Nc + n0+tx]);
      __syncthreads();
#pragma unroll
      for(int i=0;i<32;i+=16)
        xT[((size_t)bb*Nc + (n0+ty+i))*CINc + c0+tx] = tile[tx][ty+i];
    }
    // ---- chore B: weight/t conversion, strided over workers ----
    {
      int gid = wid*512 + tid;
      const int stride = NWORK*512;
      short* p = wbf;
      for(int i=gid; i<COUTc*CINc; i+=stride) p[i] = f2b(Wproj[i]);
      p += COUTc*CINc;
      for(int i=gid; i<COUTc*COUTc; i+=stride) p[i] = f2b(Wl1[i]);
      p += COUTc*COUTc;
      for(int i=gid; i<COUTc*COUTc; i+=stride) p[i] = f2b(Wl2[i]);
      p += COUTc*COUTc;
      for(int i=gid; i<COUTc*COUTc; i+=stride) p[i] = f2b(Wc1[i]);
      p += COUTc*COUTc;
      for(int i=gid; i<COUTc*COUTc; i+=stride) p[i] = f2b(Wc2[i]);
      p += COUTc*COUTc;
      for(int i=gid; i<TCHc*COUTc; i+=stride) p[i] = f2b(Wk[i]);
      p += TCHc*COUTc;
      for(int i=gid; i<TCHc*COUTc; i+=stride) p[i] = f2b(Wv[i]);
      p += TCHc*COUTc;
      for(int i=gid; i<TCHc*TCHc; i+=stride) p[i] = f2b(Wq[i]);
      p += TCHc*TCHc;
      for(int i=gid; i<TCHc*TCHc; i+=stride) p[i] = f2b(Wo[i]);
      p += TCHc*TCHc;
      for(int i=gid; i<3*TCHc*TCHc; i+=stride) p[i] = f2b(Wqkv[i]);
      p += 3*TCHc*TCHc;
      for(int i=gid; i<TCHc*TCHc; i+=stride) p[i] = f2b(Wao[i]);
      p += TCHc*TCHc;
      for(int i=gid; i<2*TCHc*TCHc; i+=stride) p[i] = f2b(Wf1[i]);
      p += 2*TCHc*TCHc;
      for(int i=gid; i<2*TCHc*TCHc; i+=stride) p[i] = f2b(Wf2[i]);
      p += 2*TCHc*TCHc;
      for(int i=gid; i<Bc*Mc*TCHc; i+=stride) p[i] = f2b(t_in[i]);
    }
    // ---- KNN: coords+dd in registers (8/thread); queries gated by polling ----
    int* s_qn = (int*)(smemc + 2112);
    double* pvd = (double*)(smemc + 2176);   // [2][8] parity-buffered partials
    const float* xb = xyz + (size_t)b*Nc*3;
    float px[8], py[8], pz[8], db[8];
#pragma unroll
    for(int j=0;j<8;j++){
      int n = tid + 512*j;
      float xx=xb[n*3], yy=xb[n*3+1], zz=xb[n*3+2];
      px[j]=xx; py[j]=yy; pz[j]=zz;
      db[j] = __fadd_rn(__fadd_rn(__fmul_rn(xx,xx),__fmul_rn(yy,yy)),__fmul_rn(zz,zz));
    }
    __syncthreads();
    for(int s = widb; s < Sc; s += 31){
      if(tid==0){
        int qn;
        for(;;){
          qn = __hip_atomic_load(&fps_idx[b*Sc + s], __ATOMIC_RELAXED, __HIP_MEMORY_SCOPE_AGENT);
          if(qn >= 0) break;
          __builtin_amdgcn_s_sleep(8);
        }
        s_qn[0] = qn & (Nc-1);
      }
      bar_lds();
      int qn = s_qn[0];
      const float* q = xyz + ((size_t)b*Nc + qn)*3;
      float sxq = q[0], syq = q[1], szq = q[2];
      if(tid < 3) out0[((size_t)b*Sc + s)*3 + tid] = q[tid];
      float ss = __fadd_rn(__fadd_rn(__fmul_rn(sxq,sxq),__fmul_rn(syq,syq)),__fmul_rn(szq,szq));
      float dv[8];
#pragma unroll
      for(int j=0;j<8;j++){
        float e = __fmul_rn(sxq,px[j]);
        e = __fadd_rn(e, __fmul_rn(syq,py[j]));
        e = __fadd_rn(e, __fmul_rn(szq,pz[j]));
        dv[j] = __fadd_rn(__fadd_rn(__fmul_rn(-2.f,e), ss), db[j]);
      }
      int* ob = knn_idx + ((size_t)b*Sc + s)*Kc;
      for(int k=0;k<Kc;k++){
        // single packed min-reduce: (dist_bits<<32)|index -> min dist, tie min idx.
        // clamp to >=0 for the PACK only: only the self-point can go negative
        // (fp cancellation); clamping keeps it the minimum and keeps all packed
        // keys positive so f64 ordering == u64 ordering (index tie-break correct).
        double kk = packkey(fmaxf(dv[0],0.f), (unsigned)tid);
#pragma unroll
        for(int j=1;j<8;j++) kk = fmin(kk, packkey(fmaxf(dv[j],0.f), (unsigned)(tid + 512*j)));
        kk = dpp_min_f64<0x111>(kk);
        kk = dpp_min_f64<0x112>(kk);
        kk = dpp_min_f64<0x114>(kk);
        kk = dpp_min_f64<0x118>(kk);
        kk = dpp_min_f64<0x142>(kk);
        kk = dpp_min_f64<0x143>(kk);
        double* pb = pvd + (k&1)*8;
        if((tid&63)==63) pb[tid>>6] = kk;
        bar_lds();
        double w0 = fmin(fmin(fmin(pb[0],pb[1]),fmin(pb[2],pb[3])),
                         fmin(fmin(pb[4],pb[5]),fmin(pb[6],pb[7])));
        int win = (int)(unsigned)(__double_as_longlong(w0) & 0xFFFFFFFFULL);
        if(tid==0) ob[k] = win;
#pragma unroll
        for(int j=0;j<8;j++) if(tid + 512*j == win) dv[j] = 3.4e38f;
      }
    }
  }
}

// ---------------- 128x128 MFMA GEMM, A/W bf16 ------------------------------
template<int HAS_BN, int HAS_GELU, int HAS_RES, typename TRES>
__global__ __launch_bounds__(256) void gemm128(
    const short* __restrict__ A, const short* __restrict__ W,
    const float* __restrict__ g, const float* __restrict__ bias,
    const TRES* __restrict__ Res, short* __restrict__ Out,
    int Nn, int Kk){
  __shared__ short As[128*32];
  __shared__ short Bs[128*32];
  int bm = blockIdx.y*128, bn = blockIdx.x*128;
  int tid = threadIdx.x;
  int wave = tid>>6, lane = tid&63, quad = lane>>4, l16 = lane&15;
  int wr = (wave>>1)*64, wc = (wave&1)*64;
  f32x4 acc[4][4];
#pragma unroll
  for(int i=0;i<4;i++)
#pragma unroll
    for(int j=0;j<4;j++) acc[i][j] = (f32x4){0.f,0.f,0.f,0.f};
  int sr = tid>>2, scc = (tid&3)*8;
  const short* Ap = A + (size_t)(bm+sr)*Kk + scc;
  const short* Wp = W + (size_t)(bn+sr)*Kk + scc;
  for(int k0=0; k0<Kk; k0+=32){
    gl_lds16(Ap + k0,                    As + tid*8);
    gl_lds16(Ap + k0 + (size_t)64*Kk,    As + 2048 + tid*8);
    gl_lds16(Wp + k0,                    Bs + tid*8);
    gl_lds16(Wp + k0 + (size_t)64*Kk,    Bs + 2048 + tid*8);
    __syncthreads();
    bf16x8 af[4], bfr[4];
#pragma unroll
    for(int mt=0; mt<4; mt++) af[mt]  = *(const bf16x8*)&As[(wr+mt*16+l16)*32 + quad*8];
#pragma unroll
    for(int nt=0; nt<4; nt++) bfr[nt] = *(const bf16x8*)&Bs[(wc+nt*16+l16)*32 + quad*8];
#pragma unroll
    for(int mt=0; mt<4; mt++)
#pragma unroll
      for(int nt=0; nt<4; nt++)
        acc[mt][nt] = __builtin_amdgcn_mfma_f32_16x16x32_bf16(af[mt], bfr[nt], acc[mt][nt], 0, 0, 0);
    __syncthreads();
  }
#pragma unroll
  for(int nt=0; nt<4; nt++){
    int col = bn + wc + nt*16 + l16;
    float gs = 0.f, bs_ = 0.f;
    if(HAS_BN){ gs = g[col] * BN_SCALE_F; bs_ = bias[col]; }
#pragma unroll
    for(int mt=0; mt<4; mt++){
#pragma unroll
      for(int r2=0;r2<4;r2++){
        int row = bm + wr + mt*16 + quad*4 + r2;
        float v = acc[mt][nt][r2];
        if(HAS_BN) v = v*gs + bs_;
        if(HAS_RES) v += rdval(Res + (size_t)row*Nn + col);
        if(HAS_GELU) v = gelu_f(v);
        Out[(size_t)row*Nn + col] = f2b(v);
      }
    }
  }
}

// ------- proj 128x128: gathered edge A, W via DMA; rows offset by R0 -------
__global__ __launch_bounds__(256) void proj128(
    const short* __restrict__ xT, const int* __restrict__ knn_idx, const int* __restrict__ fps_idx,
    const short* __restrict__ W, const float* __restrict__ g, const float* __restrict__ bias,
    short* __restrict__ Out, int R0){
  __shared__ short As[128*32];
  __shared__ short Bs[128*32];
  int bm = blockIdx.y*128, bn = blockIdx.x*128;
  int tid = threadIdx.x;
  int wave = tid>>6, lane = tid&63, quad = lane>>4, l16 = lane&15;
  int wr = (wave>>1)*64, wc = (wave&1)*64;
  f32x4 acc[4][4];
#pragma unroll
  for(int i=0;i<4;i++)
#pragma unroll
    for(int j=0;j<4;j++) acc[i][j] = (f32x4){0.f,0.f,0.f,0.f};
  int sr = tid>>2, scc = (tid&3)*8;
  int Rg0 = R0 + bm + sr, Rg1 = Rg0 + 64;
  int b0 = Rg0 / (Sc*Kc), b1 = Rg1 / (Sc*Kc);
  int nk0 = knn_idx[Rg0] & (Nc-1), nk1 = knn_idx[Rg1] & (Nc-1);
  int nc0 = fps_idx[Rg0 / Kc] & (Nc-1), nc1 = fps_idx[Rg1 / Kc] & (Nc-1);
  const short* pk0 = xT + ((size_t)b0*Nc + nk0)*CINc + scc;
  const short* pc0 = xT + ((size_t)b0*Nc + nc0)*CINc + scc;
  const short* pk1 = xT + ((size_t)b1*Nc + nk1)*CINc + scc;
  const short* pc1 = xT + ((size_t)b1*Nc + nc1)*CINc + scc;
  const short* Wp  = W + (size_t)(bn+sr)*CINc + scc;
  for(int k0=0; k0<CINc; k0+=32){
    gl_lds16(Wp + k0,                      Bs + tid*8);
    gl_lds16(Wp + k0 + (size_t)64*CINc,    Bs + 2048 + tid*8);
    bf16x8 vk = *(const bf16x8*)(pk0 + k0);
    bf16x8 vc = *(const bf16x8*)(pc0 + k0);
    bf16x8 e0, e1;
#pragma unroll
    for(int i=0;i<8;i++) e0[i] = f2b(__fsub_rn(b2f(vk[i]), b2f(vc[i])));
    vk = *(const bf16x8*)(pk1 + k0);
    vc = *(const bf16x8*)(pc1 + k0);
#pragma unroll
    for(int i=0;i<8;i++) e1[i] = f2b(__fsub_rn(b2f(vk[i]), b2f(vc[i])));
    *(bf16x8*)&As[tid*8] = e0;
    *(bf16x8*)&As[2048 + tid*8] = e1;
    __syncthreads();
    bf16x8 af[4], bfr[4];
#pragma unroll
    for(int mt=0; mt<4; mt++) af[mt]  = *(const bf16x8*)&As[(wr+mt*16+l16)*32 + quad*8];
#pragma unroll
    for(int nt=0; nt<4; nt++) bfr[nt] = *(const bf16x8*)&Bs[(wc+nt*16+l16)*32 + quad*8];
#pragma unroll
    for(int mt=0; mt<4; mt++)
#pragma unroll
      for(int nt=0; nt<4; nt++)
        acc[mt][nt] = __builtin_amdgcn_mfma_f32_16x16x32_bf16(af[mt], bfr[nt], acc[mt][nt], 0, 0, 0);
    __syncthreads();
  }
#pragma unroll
  for(int nt=0; nt<4; nt++){
    int col = bn + wc + nt*16 + l16;
    float gs = g[col] * BN_SCALE_F, bs_ = bias[col];
#pragma unroll
    for(int mt=0; mt<4; mt++){
#pragma unroll
      for(int r2=0;r2<4;r2++){
        int row = bm + wr + mt*16 + quad*4 + r2;
        float v = acc[mt][nt][r2]*gs + bs_;
        Out[(size_t)row*COUTc + col] = f2b(gelu_f(v));
      }
    }
  }
}

// -- l2 GEMM + residual + gelu + max over k (BM=48), A & W bf16 via DMA -----
__global__ __launch_bounds__(192) void gemm_l2max(
    const short* __restrict__ A, const short* __restrict__ W,
    const float* __restrict__ g, const float* __restrict__ bias,
    const short* __restrict__ Hres, short* __restrict__ Fout, int R0){
  __shared__ short As[48*32];
  __shared__ short Bs[64*32];
  __shared__ float sm[48][65];
  int bm = blockIdx.y*48, bn = blockIdx.x*64;
  int tid = threadIdx.x;
  int wave = tid >> 6, lane = tid & 63, quad = lane >> 4, l16 = lane & 15;
  f32x4 acc[4];
#pragma unroll
  for(int i=0;i<4;i++) acc[i] = (f32x4){0.f,0.f,0.f,0.f};
  const short* Ap  = A + (size_t)(bm + (tid>>2))*COUTc + (tid&3)*8;
  const short* Wp  = W + (size_t)(bn + (tid>>2))*COUTc + (tid&3)*8;
  const short* Wp2 = W + (size_t)(bn + 48 + (lane>>2))*COUTc + (lane&3)*8;
  for(int k0=0; k0<COUTc; k0+=32){
    gl_lds16(Ap + k0, As + tid*8);
    gl_lds16(Wp + k0, Bs + tid*8);
    if(wave==0) gl_lds16(Wp2 + k0, Bs + 1536 + lane*8);
    __syncthreads();
    bf16x8 a = *(const bf16x8*)&As[(wave*16 + l16)*32 + quad*8];
#pragma unroll
    for(int ct=0; ct<4; ct++){
      bf16x8 bb = *(const bf16x8*)&Bs[(ct*16 + l16)*32 + quad*8];
      acc[ct] = __builtin_amdgcn_mfma_f32_16x16x32_bf16(a, bb, acc[ct], 0, 0, 0);
    }
    __syncthreads();
  }
#pragma unroll
  for(int ct=0; ct<4; ct++){
    int col = bn + ct*16 + l16;
    float gs = g[col] * BN_SCALE_F, bs_ = bias[col];
#pragma unroll
    for(int r2=0;r2<4;r2++){
      int rl = wave*16 + quad*4 + r2;
      float v = acc[ct][r2]*gs + bs_;
      v += b2f(Hres[(size_t)(bm+rl)*COUTc + col]);
      sm[rl][ct*16 + l16] = gelu_f(v);
    }
  }
  __syncthreads();
  if(tid < 128){
    int gl = tid >> 6, col = tid & 63;
    float mx = -3.4e38f;
#pragma unroll
    for(int kk=0; kk<Kc; kk++) mx = fmaxf(mx, sm[gl*Kc + kk][col]);
    int gg = R0/Kc + blockIdx.y*2 + gl;   // global (b*Sc+s)
    Fout[(size_t)gg*COUTc + bn + col] = f2b(mx);
  }
}

// ------- 64x64 MFMA GEMM, A & W bf16, both staged via global_load_lds ------
template<int HAS_BN, int HAS_GELU, int HAS_RES, typename TRES, typename TOUT>
__global__ __launch_bounds__(256) void gemm64d(
    const short* __restrict__ A, const short* __restrict__ W,
    const float* __restrict__ g, const float* __restrict__ bias,
    const TRES* __restrict__ Res, TOUT* __restrict__ Out,
    int Nn, int Kk){
  __shared__ short As[64*32];
  __shared__ short Bs[64*32];
  int bm = blockIdx.y*64, bn = blockIdx.x*64;
  int tid = threadIdx.x;
  int wave = tid >> 6, lane = tid & 63, quad = lane >> 4, l16 = lane & 15;
  f32x4 acc[4];
#pragma unroll
  for(int i=0;i<4;i++) acc[i] = (f32x4){0.f,0.f,0.f,0.f};
  const short* Ap = A + (size_t)(bm + (tid>>2))*Kk + (tid&3)*8;
  const short* Wp = W + (size_t)(bn + (tid>>2))*Kk + (tid&3)*8;
  for(int k0=0; k0<Kk; k0+=32){
    gl_lds16(Ap + k0, As + tid*8);
    gl_lds16(Wp + k0, Bs + tid*8);
    __syncthreads();
    bf16x8 a = *(const bf16x8*)&As[(wave*16 + l16)*32 + quad*8];
#pragma unroll
    for(int ct=0; ct<4; ct++){
      bf16x8 bb = *(const bf16x8*)&Bs[(ct*16 + l16)*32 + quad*8];
      acc[ct] = __builtin_amdgcn_mfma_f32_16x16x32_bf16(a, bb, acc[ct], 0, 0, 0);
    }
    __syncthreads();
  }
#pragma unroll
  for(int ct=0; ct<4; ct++){
    int col = bn + ct*16 + l16;
    float gs = 0.f, bs_ = 0.f;
    if(HAS_BN){ gs = g[col] * BN_SCALE_F; bs_ = bias[col]; }
#pragma unroll
    for(int r2=0;r2<4;r2++){
      int row = bm + wave*16 + quad*4 + r2;
      float v = acc[ct][r2];
      if(HAS_BN) v = v*gs + bs_;
      if(HAS_RES) v += rdval(Res + (size_t)row*Nn + col);
      if(HAS_GELU) v = gelu_f(v);
      wrval(Out + (size_t)row*Nn + col, v);
    }
  }
}

// ---------------- f2 [B,S,C] bf16 -> x_out [B,C,S] f32 ---------------------
__global__ __launch_bounds__(256) void transpose_f(const short* __restrict__ f2, float* __restrict__ out1){
  __shared__ short tile[32][33];
  int b = blockIdx.z;
  int s0 = blockIdx.x*32, c0 = blockIdx.y*32;
  int tx = threadIdx.x & 31, ty = threadIdx.x >> 5;
#pragma unroll
  for(int i=0;i<32;i+=8)
    tile[ty+i][tx] = f2[((size_t)b*Sc + (s0+ty+i))*COUTc + c0+tx];
  __syncthreads();
#pragma unroll
  for(int i=0;i<32;i+=8)
    out1[((size_t)b*COUTc + (c0+ty+i))*Sc + s0+tx] = b2f(tile[tx][ty+i]);
}

// ------- Local2Former attention: block per (b,m); kv packed [row,512] ------
__global__ __launch_bounds__(256) void l2f_attn(
    const short* __restrict__ qb, const short* __restrict__ kv,
    short* __restrict__ ao){
  int blk = blockIdx.x; int b = blk / Mc; int m = blk % Mc;
  int tid = threadIdx.x;
  __shared__ float qs[TCHc];
  __shared__ float aw[Sc];
  __shared__ float red[8];
  qs[tid] = b2f(qb[(size_t)(b*Mc+m)*TCHc + tid]);
  __syncthreads();
  float sc[4];
#pragma unroll
  for(int jj=0;jj<4;jj++){
    int j = tid + 256*jj;
    const short* kp = kv + ((size_t)b*Sc + j)*512;
    float a = 0.f;
    for(int c=0;c<TCHc;c+=8){
      bf16x8 v8 = *(const bf16x8*)(kp + c);
#pragma unroll
      for(int i=0;i<8;i++) a += b2f(v8[i]) * qs[c+i];
    }
    sc[jj] = a * 0.0625f;   // TCH^-0.5
  }
  float mx = fmaxf(fmaxf(sc[0],sc[1]), fmaxf(sc[2],sc[3]));
#pragma unroll
  for(int off=32; off>0; off>>=1) mx = fmaxf(mx, __shfl_xor(mx, off));
  if((tid&63)==0) red[tid>>6] = mx;
  __syncthreads();
  mx = fmaxf(fmaxf(red[0],red[1]), fmaxf(red[2],red[3]));
  float se = 0.f;
#pragma unroll
  for(int jj=0;jj<4;jj++){
    float e = expf(sc[jj] - mx);
    aw[tid + 256*jj] = e;
    se += e;
  }
#pragma unroll
  for(int off=32; off>0; off>>=1) se += __shfl_xor(se, off);
  if((tid&63)==0) red[4 + (tid>>6)] = se;
  __syncthreads();
  se = red[4]+red[5]+red[6]+red[7];
  float inv = 1.f/se;
#pragma unroll
  for(int jj=0;jj<4;jj++) aw[tid + 256*jj] *= inv;
  __syncthreads();
  float acc = 0.f;
  const short* vp = kv + (size_t)b*Sc*512 + 256 + tid;
  for(int j=0;j<Sc;j++) acc += aw[j] * b2f(vp[(size_t)j*512]);
  ao[(size_t)(b*Mc+m)*TCHc + tid] = f2b(acc);
}

// ---------------- Former MHA: block per (b,h,m), 64 threads ----------------
__global__ __launch_bounds__(64) void former_attn(const short* __restrict__ qkv, short* __restrict__ oa){
  int blk = blockIdx.x;
  int m = blk % Mc; int bh = blk / Mc; int h = bh % Hc; int b = bh / Hc;
  int lane = threadIdx.x;
  __shared__ float qs[HDc];
  __shared__ float aw2[32];
  const short* base = qkv + (size_t)(b*Mc)*(3*TCHc);
  qs[lane] = b2f(base[(size_t)m*3*TCHc + h*HDc + lane]);
  __syncthreads();
  int j = lane & 31;
  const short* kp = base + (size_t)j*3*TCHc + TCHc + h*HDc;
  float s = 0.f;
  for(int d=0; d<HDc; d+=8){
    bf16x8 v8 = *(const bf16x8*)(kp + d);
#pragma unroll
    for(int i=0;i<8;i++) s += b2f(v8[i]) * qs[d+i];
  }
  s *= 0.125f;  // HD^-0.5
  float mx = s;
#pragma unroll
  for(int off=16; off>0; off>>=1) mx = fmaxf(mx, __shfl_xor(mx, off, 32));
  float e = expf(s - mx);
  float se = e;
#pragma unroll
  for(int off=16; off>0; off>>=1) se += __shfl_xor(se, off, 32);
  if(lane < 32) aw2[lane] = e / se;
  __syncthreads();
  float acc = 0.f;
  const short* vp = base + 2*TCHc + h*HDc + lane;
  for(int jj=0; jj<32; jj++) acc += aw2[jj] * b2f(vp[(size_t)jj*3*TCHc]);
  oa[(size_t)(b*Mc+m)*TCHc + h*HDc + lane] = f2b(acc);
}

// ---------------- LayerNorm over 256: f32 in, bf16 out ---------------------
__global__ __launch_bounds__(64) void ln_kernel(const float* __restrict__ X, const float* __restrict__ g,
                                                const float* __restrict__ bb, short* __restrict__ O){
  int row = blockIdx.x, lane = threadIdx.x;
  const float* xp = X + (size_t)row*TCHc;
  float x[4];
#pragma unroll
  for(int j2=0;j2<4;j2++) x[j2] = xp[lane + 64*j2];
  float sm = x[0]+x[1]+x[2]+x[3];
#pragma unroll
  for(int off=32; off>0; off>>=1) sm += __shfl_xor(sm, off);
  float mu = sm * (1.f/256.f);
  float vs = 0.f;
#pragma unroll
  for(int j2=0;j2<4;j2++){ float d = x[j2]-mu; vs += d*d; }
#pragma unroll
  for(int off=32; off>0; off>>=1) vs += __shfl_xor(vs, off);
  float var = vs * (1.f/256.f);
  float rstd = 1.f / sqrtf(var + 1e-5f);
#pragma unroll
  for(int j2=0;j2<4;j2++){
    int c = lane + 64*j2;
    float o = (x[j2]-mu)*rstd*g[c] + bb[c];
    O[(size_t)row*TCHc + c] = f2b(o);
  }
}

extern "C" void kernel_launch(void* const* d_in, const int* in_sizes, int n_in,
                              void* d_out, int out_size, void* d_ws, size_t ws_size,
                              hipStream_t stream){
  const float* xyz  = (const float*)d_in[0];
  const float* x    = (const float*)d_in[1];
  const float* t_in = (const float*)d_in[2];
  const int*   far0 = (const int*)d_in[3];
  const float* Wproj=(const float*)d_in[4];  const float* gproj=(const float*)d_in[5];  const float* bproj=(const float*)d_in[6];
  const float* Wl1 = (const float*)d_in[7];  const float* gl1 = (const float*)d_in[8];  const float* bl1 = (const float*)d_in[9];
  const float* Wl2 = (const float*)d_in[10]; const float* gl2 = (const float*)d_in[11]; const float* bl2 = (const float*)d_in[12];
  const float* Wc1 = (const float*)d_in[13]; const float* gc1 = (const float*)d_in[14]; const float* bc1 = (const float*)d_in[15];
  const float* Wc2 = (const float*)d_in[16]; const float* gc2 = (const float*)d_in[17]; const float* bc2 = (const float*)d_in[18];
  const float* Wq  = (const float*)d_in[19]; const float* Wk  = (const float*)d_in[20]; const float* Wv  = (const float*)d_in[21];
  const float* Wo  = (const float*)d_in[22];
  const float* ln1g= (const float*)d_in[23]; const float* ln1b= (const float*)d_in[24];
  const float* Wqkv= (const float*)d_in[25]; const float* Wao = (const float*)d_in[26];
  const float* ln2g= (const float*)d_in[27]; const float* ln2b= (const float*)d_in[28];
  const float* Wf1 = (const float*)d_in[29]; const float* Wf2 = (const float*)d_in[30];

  char* wsb = (char*)d_ws;
  size_t off = 0;
  auto alloc = [&](size_t bytes)->void*{ void* p = wsb + off; off += (bytes + 255) & ~(size_t)255; return p; };
  int*   fps_i = (int*)alloc((size_t)Bc*Sc*4);
  int*   knn   = (int*)alloc((size_t)Bc*Sc*Kc*4);
  short* xT    = (short*)alloc((size_t)Bc*Nc*CINc*2);
  // bf16 pool: proj,l1,l2,c1,c2,k,v,q,o,qkv,ao,f1,f2,t
  size_t wbf_elems = (size_t)COUTc*CINc + 4*(size_t)COUTc*COUTc + 2*(size_t)TCHc*COUTc
                   + 2*(size_t)TCHc*TCHc + 3*(size_t)TCHc*TCHc + (size_t)TCHc*TCHc
                   + 2*(size_t)TCHc*TCHc + 2*(size_t)TCHc*TCHc + (size_t)Bc*Mc*TCHc;
  short* wbf   = (short*)alloc(wbf_elems*2);
  short* fbuf  = (short*)alloc((size_t)Bc*Sc*COUTc*2);
  short* rcbuf = (short*)alloc((size_t)Bc*Sc*COUTc*2);
  short* f2buf = (short*)alloc((size_t)Bc*Sc*COUTc*2);
  short* kvbuf = (short*)alloc((size_t)Bc*Sc*512*2);
  short* qbuf  = (short*)alloc((size_t)Bc*Mc*TCHc*2);
  short* a1out = (short*)alloc((size_t)Bc*Mc*TCHc*2);
  float* t1buf = (float*)alloc((size_t)Bc*Mc*TCHc*4);
  short* hnbuf = (short*)alloc((size_t)Bc*Mc*TCHc*2);
  short* qkvb  = (short*)alloc((size_t)Bc*Mc*3*TCHc*2);
  short* a2out = (short*)alloc((size_t)Bc*Mc*TCHc*2);
  float* t2buf = (float*)alloc((size_t)Bc*Mc*TCHc*4);
  short* hn2buf= (short*)alloc((size_t)Bc*Mc*TCHc*2);
  short* g1buf = (short*)alloc((size_t)Bc*Mc*2*TCHc*2);
  size_t full_bytes  = (size_t)Bc*MBAT*COUTc*2;   // ~96 MB
  size_t batch_bytes = (size_t)MBAT*COUTc*2;      // ~12 MB
  bool batched = (off + 2*(full_bytes + 256) <= ws_size);
  short* hbuf = (short*)alloc(batched ? full_bytes : batch_bytes);
  short* rbuf = (short*)alloc(batched ? full_bytes : batch_bytes);
  if(off > ws_size) return;  // insufficient workspace; fail visibly

  short* wproj_bf = wbf;
  short* wl1_bf   = wproj_bf + COUTc*CINc;
  short* wl2_bf   = wl1_bf + COUTc*COUTc;
  short* wc1_bf   = wl2_bf + COUTc*COUTc;
  short* wc2_bf   = wc1_bf + COUTc*COUTc;
  short* wkv_bf   = wc2_bf + COUTc*COUTc;     // [512,256]
  short* wq_bf    = wkv_bf + 2*TCHc*COUTc;
  short* wo_bf    = wq_bf + TCHc*TCHc;
  short* wqkv_bf  = wo_bf + TCHc*TCHc;
  short* wao_bf   = wqkv_bf + 3*TCHc*TCHc;
  short* wf1_bf   = wao_bf + TCHc*TCHc;
  short* wf2_bf   = wf1_bf + 2*TCHc*TCHc;
  short* tbf      = wf2_bf + 2*TCHc*TCHc;     // t_in as bf16

  float* out0 = (float*)d_out;
  float* out1 = out0 + (size_t)Bc*Sc*3;
  float* out2 = out1 + (size_t)Bc*COUTc*Sc;

  // --- prep+knn: fps publishes winners (relaxed); workers poll fps_idx ---
  hipMemsetAsync(fps_i, 0xFF, (size_t)Bc*Sc*4, stream);   // sentinel: -1 = not yet written
  prep_kernel<<<PREP_TOTAL, 512, 0, stream>>>(xyz, far0, fps_i, x, xT,
                                              Wproj, Wl1, Wl2, Wc1, Wc2, Wk, Wv,
                                              Wq, Wo, Wqkv, Wao, Wf1, Wf2, t_in,
                                              wbf, knn, out0);
  // --- Local (round-10 proven config) ---
  if(batched){
    proj128<<<dim3(COUTc/128, (Bc*MBAT)/128), 256, 0, stream>>>(xT, knn, fps_i, wproj_bf, gproj, bproj, hbuf, 0);
    gemm128<1,1,0,short><<<dim3(COUTc/128, (Bc*MBAT)/128), 256, 0, stream>>>(hbuf, wl1_bf, gl1, bl1, (const short*)nullptr, rbuf, COUTc, COUTc);
    gemm_l2max<<<dim3(COUTc/64, (Bc*MBAT)/48), 192, 0, stream>>>(rbuf, wl2_bf, gl2, bl2, hbuf, fbuf, 0);
  } else {
    for(int b=0; b<Bc; b++){
      proj128<<<dim3(COUTc/128, MBAT/128), 256, 0, stream>>>(xT, knn, fps_i, wproj_bf, gproj, bproj, hbuf, b*MBAT);
      gemm128<1,1,0,short><<<dim3(COUTc/128, MBAT/128), 256, 0, stream>>>(hbuf, wl1_bf, gl1, bl1, (const short*)nullptr, rbuf, COUTc, COUTc);
      gemm_l2max<<<dim3(COUTc/64, MBAT/48), 192, 0, stream>>>(rbuf, wl2_bf, gl2, bl2, hbuf, fbuf, b*MBAT);
    }
  }
  // --- Channel ---
  gemm64d<1,1,0,short,short><<<dim3(COUTc/64, (Bc*Sc)/64), 256, 0, stream>>>(fbuf, wc1_bf, gc1, bc1, (const short*)nullptr, rcbuf, COUTc, COUTc);
  gemm64d<1,1,1,short,short><<<dim3(COUTc/64, (Bc*Sc)/64), 256, 0, stream>>>(rcbuf, wc2_bf, gc2, bc2, fbuf, f2buf, COUTc, COUTc);
  transpose_f<<<dim3(Sc/32, COUTc/32, Bc), 256, 0, stream>>>(f2buf, out1);
  // --- Local2Former ---
  gemm64d<0,0,0,short,short><<<dim3(TCHc/64, (Bc*Mc)/64), 256, 0, stream>>>(tbf, wq_bf, nullptr, nullptr, (const short*)nullptr, qbuf, TCHc, TCHc);
  gemm64d<0,0,0,short,short><<<dim3(512/64, (Bc*Sc)/64), 256, 0, stream>>>(f2buf, wkv_bf, nullptr, nullptr, (const short*)nullptr, kvbuf, 512, COUTc);
  l2f_attn<<<Bc*Mc, 256, 0, stream>>>(qbuf, kvbuf, a1out);
  gemm64d<0,0,1,float,float><<<dim3(TCHc/64, (Bc*Mc)/64), 256, 0, stream>>>(a1out, wo_bf, nullptr, nullptr, t_in, t1buf, TCHc, TCHc);
  // --- Former ---
  ln_kernel<<<Bc*Mc, 64, 0, stream>>>(t1buf, ln1g, ln1b, hnbuf);
  gemm64d<0,0,0,short,short><<<dim3((3*TCHc)/64, (Bc*Mc)/64), 256, 0, stream>>>(hnbuf, wqkv_bf, nullptr, nullptr, (const short*)nullptr, qkvb, 3*TCHc, TCHc);
  former_attn<<<Bc*Hc*Mc, 64, 0, stream>>>(qkvb, a2out);
  gemm64d<0,0,1,float,float><<<dim3(TCHc/64, (Bc*Mc)/64), 256, 0, stream>>>(a2out, wao_bf, nullptr, nullptr, t1buf, t2buf, TCHc, TCHc);
  ln_kernel<<<Bc*Mc, 64, 0, stream>>>(t2buf, ln2g, ln2b, hn2buf);
  gemm64d<0,1,0,short,short><<<dim3((2*TCHc)/64, (Bc*Mc)/64), 256, 0, stream>>>(hn2buf, wf1_bf, nullptr, nullptr, (const short*)nullptr, g1buf, 2*TCHc, TCHc);
  gemm64d<0,0,1,float,float><<<dim3(TCHc/64, (Bc*Mc)/64), 256, 0, stream>>>(g1buf, wf2_bf, nullptr, nullptr, t2buf, out2, TCHc, 2*TCHc);
}

// Round 7
// 1100.272 us; speedup vs baseline: 1.4785x; 1.1039x over previous
//
#include <hip/hip_runtime.h>
#include <math.h>

#define Bc 8
#define Nc 4096
#define CINc 128
#define COUTc 256
#define Sc 1024
#define Kc 24
#define TCHc 256
#define Mc 32
#define Hc 4
#define HDc 64
#define MBAT (Sc*Kc)      // rows per batch in Local stage: 24576

#define BN_SCALE_F 0.9999950000374997f

typedef __attribute__((ext_vector_type(8))) short bf16x8;
typedef __attribute__((ext_vector_type(4))) float f32x4;

__device__ __forceinline__ float b2f(short s){
  unsigned int u = ((unsigned int)(unsigned short)s) << 16;
  union { unsigned int u; float f; } c; c.u = u; return c.f;
}
__device__ __forceinline__ short f2b(float f){
  union { unsigned int u; float f; } c; c.f = f;
  unsigned int u = c.u;
  unsigned int r = (u + 0x7fffu + ((u >> 16) & 1u)) >> 16;
  return (short)(r & 0xffffu);
}
__device__ __forceinline__ float gelu_f(float v){
  return 0.5f * v * (1.f + erff(v * 0.7071067811865475f));
}
__device__ __forceinline__ float rdval(const float* p){ return *p; }
__device__ __forceinline__ float rdval(const short* p){ return b2f(*p); }
__device__ __forceinline__ void wrval(float* p, float v){ *p = v; }
__device__ __forceinline__ void wrval(short* p, float v){ *p = f2b(v); }

// async global->LDS, 16B per lane (dest follows lane order: base + lane*16B)
__device__ __forceinline__ void gl_lds16(const short* g, short* l){
  __builtin_amdgcn_global_load_lds(
     (const __attribute__((address_space(1))) void*)g,
     (__attribute__((address_space(3))) void*)l, 16, 0, 0);
}

// barrier that drains ONLY LDS ops (lgkmcnt), leaving global stores in flight.
__device__ __forceinline__ void bar_lds(){
  asm volatile("s_waitcnt lgkmcnt(0)" ::: "memory");
  __builtin_amdgcn_s_barrier();
}

template<int CTRL>
__device__ __forceinline__ double dpp_max_f64(double v){
  long long x = __double_as_longlong(v);
  int lo = (int)(unsigned int)(x & 0xFFFFFFFFLL);
  int hi = (int)(unsigned int)((unsigned long long)x >> 32);
  int plo = __builtin_amdgcn_update_dpp(lo, lo, CTRL, 0xF, 0xF, false);
  int phi = __builtin_amdgcn_update_dpp(hi, hi, CTRL, 0xF, 0xF, false);
  double p = __longlong_as_double((long long)(((unsigned long long)(unsigned int)phi << 32)
                                              | (unsigned int)plo));
  return fmax(v, p);
}
template<int CTRL>
__device__ __forceinline__ float dpp_min_f32(float v){
  int x = __float_as_int(v);
  int p = __builtin_amdgcn_update_dpp(x, x, CTRL, 0xF, 0xF, false);
  return fminf(v, __int_as_float(p));
}
template<int CTRL>
__device__ __forceinline__ float dpp_max_f32(float v){
  int x = __float_as_int(v);
  int p = __builtin_amdgcn_update_dpp(x, x, CTRL, 0xF, 0xF, false);
  return fmaxf(v, __int_as_float(p));
}
template<int CTRL>
__device__ __forceinline__ unsigned dpp_min_u32(unsigned v){
  int p = __builtin_amdgcn_update_dpp((int)v, (int)v, CTRL, 0xF, 0xF, false);
  unsigned pu = (unsigned)p;
  return v < pu ? v : pu;
}
// full-wave f32 reduce, result valid in lane 63
__device__ __forceinline__ float wave_min63(float v){
  v = dpp_min_f32<0x111>(v); v = dpp_min_f32<0x112>(v); v = dpp_min_f32<0x114>(v);
  v = dpp_min_f32<0x118>(v); v = dpp_min_f32<0x142>(v); v = dpp_min_f32<0x143>(v);
  return v;
}
__device__ __forceinline__ float wave_max63(float v){
  v = dpp_max_f32<0x111>(v); v = dpp_max_f32<0x112>(v); v = dpp_max_f32<0x114>(v);
  v = dpp_max_f32<0x118>(v); v = dpp_max_f32<0x142>(v); v = dpp_max_f32<0x143>(v);
  return v;
}
__device__ __forceinline__ float bcast63(float v){
  return __int_as_float(__builtin_amdgcn_readlane(__float_as_int(v), 63));
}

// ------- prep+knn mega-kernel: 256 blocks (1/CU), 512 threads (8 waves) ----
// VERBATIM revert to the round-2 proven version (prep 596.9 us, total 1132).
#define PREP_FPS 8
#define PREP_TOTAL 256
#define NWORK 248          // 31 workers per batch

__global__ __launch_bounds__(512) void prep_kernel(
    const float* __restrict__ xyz, const int* __restrict__ far0, int* __restrict__ fps_idx,
    const float* __restrict__ x, short* __restrict__ xT,
    const float* __restrict__ Wproj, const float* __restrict__ Wl1, const float* __restrict__ Wl2,
    const float* __restrict__ Wc1, const float* __restrict__ Wc2,
    const float* __restrict__ Wk, const float* __restrict__ Wv,
    const float* __restrict__ Wq, const float* __restrict__ Wo,
    const float* __restrict__ Wqkv, const float* __restrict__ Wao,
    const float* __restrict__ Wf1, const float* __restrict__ Wf2,
    const float* __restrict__ t_in,
    short* __restrict__ wbf,
    int* __restrict__ knn_idx, float* __restrict__ out0){
  // layout: sxyz f32[4096*3] @0 (49152) | sid u16[4096] @49152 (8192)
  //         hist i32[64] @57344 (256)   | pwave f64[16] @57600 (128)
  __shared__ __align__(16) char smemc[57728];
  int bid = blockIdx.x, tid = threadIdx.x;
  if(bid < PREP_FPS){
    int b = bid;
    float* sxyz = (float*)smemc;
    unsigned short* sid = (unsigned short*)(smemc + 49152);
    int* hist = (int*)(smemc + 57344);
    double* pwave = (double*)(smemc + 57600);
    const float* xb = xyz + (size_t)b*Nc*3;
    // ---- phase 1: read points, Morton(2-bit/dim) code, histogram ----
    if(tid < 64) hist[tid] = 0;
    float gx[8], gy[8], gz[8]; int code[8];
    __syncthreads();
#pragma unroll
    for(int j=0;j<8;j++){
      int n = tid + 512*j;
      const float* p = xb + n*3;
      gx[j]=p[0]; gy[j]=p[1]; gz[j]=p[2];
      int qx = (int)fminf(fmaxf((gx[j]+4.2f)*(4.f/8.4f),0.f),3.f);
      int qy = (int)fminf(fmaxf((gy[j]+4.2f)*(4.f/8.4f),0.f),3.f);
      int qz = (int)fminf(fmaxf((gz[j]+4.2f)*(4.f/8.4f),0.f),3.f);
      code[j] = ((qx>>1)<<5)|((qy>>1)<<4)|((qz>>1)<<3)|((qx&1)<<2)|((qy&1)<<1)|(qz&1);
      atomicAdd(&hist[code[j]], 1);
    }
    __syncthreads();
    // ---- phase 2: exclusive scan in place ----
    if(tid==0){
      int run=0;
      for(int i=0;i<64;i++){ int h=hist[i]; hist[i]=run; run+=h; }
    }
    __syncthreads();
    // ---- phase 3: scatter into Morton-sorted order ----
#pragma unroll
    for(int j=0;j<8;j++){
      int slot = atomicAdd(&hist[code[j]], 1);
      sxyz[slot*3]=gx[j]; sxyz[slot*3+1]=gy[j]; sxyz[slot*3+2]=gz[j];
      sid[slot] = (unsigned short)(tid + 512*j);
    }
    __syncthreads();
    // ---- phase 4: load chunked working set (wave w owns [w*512,w*512+512)) ----
    float px[8], py[8], pz[8], dmin[8];
    unsigned int lokey[8];
    float mnx=3e38f,mny=3e38f,mnz=3e38f,mxx=-3e38f,mxy=-3e38f,mxz=-3e38f;
#pragma unroll
    for(int j=0;j<8;j++){
      int i = (tid>>6)*512 + j*64 + (tid&63);
      float xx=sxyz[i*3], yy=sxyz[i*3+1], zz=sxyz[i*3+2];
      px[j]=xx; py[j]=yy; pz[j]=zz;
      dmin[j]=1e10f;
      lokey[j]=(unsigned int)((Nc-1) - (int)sid[i]);
      mnx=fminf(mnx,xx); mxx=fmaxf(mxx,xx);
      mny=fminf(mny,yy); mxy=fmaxf(mxy,yy);
      mnz=fminf(mnz,zz); mxz=fmaxf(mxz,zz);
    }
    float bbmnx = bcast63(wave_min63(mnx)), bbmxx = bcast63(wave_max63(mxx));
    float bbmny = bcast63(wave_min63(mny)), bbmxy = bcast63(wave_max63(mxy));
    float bbmnz = bcast63(wave_min63(mnz)), bbmxz = bcast63(wave_max63(mxz));
    __syncthreads();
    // ---- phase 5: restore ORIGINAL-order coords for winner lookup ----
    for(int i=tid; i<Nc; i+=512){
      const float* p = xb + i*3;
      sxyz[i*3]=p[0]; sxyz[i*3+1]=p[1]; sxyz[i*3+2]=p[2];
    }
    __syncthreads();
    // ---- main FPS loop ----
    int winner = far0[b] & (Nc-1);
    int* out = fps_idx + b*Sc;
    double pk = 0.0;          // cached per-wave partial key (valid in lane 63)
    float wm = 3.0e38f;       // cached wave max dmin (uniform)
    for(int it=0; it<Sc; it++){
      if(tid==0)
        __hip_atomic_store(&out[it], winner, __ATOMIC_RELAXED, __HIP_MEMORY_SCOPE_AGENT);
      float cx=sxyz[winner*3], cy=sxyz[winner*3+1], cz=sxyz[winner*3+2];
      // conservative BB test: skip only if provably no dmin can change
      float ddx = fmaxf(fmaxf(bbmnx - cx, cx - bbmxx), 0.f);
      float ddy = fmaxf(fmaxf(bbmny - cy, cy - bbmxy), 0.f);
      float ddz = fmaxf(fmaxf(bbmnz - cz, cz - bbmxz), 0.f);
      float md2 = ddx*ddx + ddy*ddy + ddz*ddz;
      if(md2 < wm*1.0001f){   // wave-uniform branch
        double key[8];
#pragma unroll
        for(int j=0;j<8;j++){
          float dx = __fsub_rn(px[j], cx);
          float dy = __fsub_rn(py[j], cy);
          float dz = __fsub_rn(pz[j], cz);
          float d = __fadd_rn(__fadd_rn(__fmul_rn(dx,dx), __fmul_rn(dy,dy)), __fmul_rn(dz,dz));
          dmin[j] = fminf(dmin[j], d);
          unsigned long long k = (((unsigned long long)__float_as_uint(dmin[j])) << 32) | lokey[j];
          key[j] = __longlong_as_double((long long)k);
        }
#pragma unroll
        for(int st=4; st>0; st>>=1)
#pragma unroll
          for(int j=0;j<st;j++) key[j] = fmax(key[j], key[j+st]);
        double kv = key[0];
        kv = dpp_max_f64<0x111>(kv);
        kv = dpp_max_f64<0x112>(kv);
        kv = dpp_max_f64<0x114>(kv);
        kv = dpp_max_f64<0x118>(kv);
        kv = dpp_max_f64<0x142>(kv);
        kv = dpp_max_f64<0x143>(kv);
        pk = kv;
        wm = __int_as_float(__builtin_amdgcn_readlane(
               (int)(__double_as_longlong(kv) >> 32), 63));
      }
      int p = it & 1;
      if((tid & 63) == 63) pwave[p*8 + (tid>>6)] = pk;
      bar_lds();
      double k0 = pwave[p*8+0], k1 = pwave[p*8+1], k2 = pwave[p*8+2], k3 = pwave[p*8+3];
      double k4 = pwave[p*8+4], k5 = pwave[p*8+5], k6 = pwave[p*8+6], k7 = pwave[p*8+7];
      double kb = fmax(fmax(fmax(k0,k1), fmax(k2,k3)), fmax(fmax(k4,k5), fmax(k6,k7)));
      unsigned long long kbits = (unsigned long long)__double_as_longlong(kb);
      winner = (Nc-1) - (int)(kbits & 0xFFFFFFFFULL);
    }
  } else {
    int wid = bid - PREP_FPS;       // 0..247
    int b = wid / 31;               // batch of this worker
    int widb = wid % 31;            // worker index within batch
    // ---- chore A: transpose_x tiles, strided over workers ----
    short (*tile)[33] = (short(*)[33])smemc;
    for(int t = wid; t < 4096; t += NWORK){
      int bb = t >> 9;
      int rem = t & 511;
      int n0 = (rem & 127) * 32;
      int c0 = (rem >> 7) * 32;
      int tx = tid & 31, ty = tid >> 5;   // ty 0..15
      __syncthreads();
#pragma unroll
      for(int i=0;i<32;i+=16)
        tile[ty+i][tx] = f2b(x[((size_t)bb*CINc + (c0+ty+i))*Nc + n0+tx]);
      __syncthreads();
#pragma unroll
      for(int i=0;i<32;i+=16)
        xT[((size_t)bb*Nc + (n0+ty+i))*CINc + c0+tx] = tile[tx][ty+i];
    }
    // ---- chore B: weight/t conversion, strided over workers ----
    {
      int gid = wid*512 + tid;
      const int stride = NWORK*512;
      short* p = wbf;
      for(int i=gid; i<COUTc*CINc; i+=stride) p[i] = f2b(Wproj[i]);
      p += COUTc*CINc;
      for(int i=gid; i<COUTc*COUTc; i+=stride) p[i] = f2b(Wl1[i]);
      p += COUTc*COUTc;
      for(int i=gid; i<COUTc*COUTc; i+=stride) p[i] = f2b(Wl2[i]);
      p += COUTc*COUTc;
      for(int i=gid; i<COUTc*COUTc; i+=stride) p[i] = f2b(Wc1[i]);
      p += COUTc*COUTc;
      for(int i=gid; i<COUTc*COUTc; i+=stride) p[i] = f2b(Wc2[i]);
      p += COUTc*COUTc;
      for(int i=gid; i<TCHc*COUTc; i+=stride) p[i] = f2b(Wk[i]);
      p += TCHc*COUTc;
      for(int i=gid; i<TCHc*COUTc; i+=stride) p[i] = f2b(Wv[i]);
      p += TCHc*COUTc;
      for(int i=gid; i<TCHc*TCHc; i+=stride) p[i] = f2b(Wq[i]);
      p += TCHc*TCHc;
      for(int i=gid; i<TCHc*TCHc; i+=stride) p[i] = f2b(Wo[i]);
      p += TCHc*TCHc;
      for(int i=gid; i<3*TCHc*TCHc; i+=stride) p[i] = f2b(Wqkv[i]);
      p += 3*TCHc*TCHc;
      for(int i=gid; i<TCHc*TCHc; i+=stride) p[i] = f2b(Wao[i]);
      p += TCHc*TCHc;
      for(int i=gid; i<2*TCHc*TCHc; i+=stride) p[i] = f2b(Wf1[i]);
      p += 2*TCHc*TCHc;
      for(int i=gid; i<2*TCHc*TCHc; i+=stride) p[i] = f2b(Wf2[i]);
      p += 2*TCHc*TCHc;
      for(int i=gid; i<Bc*Mc*TCHc; i+=stride) p[i] = f2b(t_in[i]);
    }
    // ---- KNN: coords+dd in registers (8/thread); queries gated by polling ----
    int* s_qn = (int*)smemc;
    float* pv = (float*)(smemc + 32);
    int*   pi = (int*)(smemc + 64);
    const float* xb = xyz + (size_t)b*Nc*3;
    float px[8], py[8], pz[8], db[8];
#pragma unroll
    for(int j=0;j<8;j++){
      int n = tid + 512*j;
      float xx=xb[n*3], yy=xb[n*3+1], zz=xb[n*3+2];
      px[j]=xx; py[j]=yy; pz[j]=zz;
      db[j] = __fadd_rn(__fadd_rn(__fmul_rn(xx,xx),__fmul_rn(yy,yy)),__fmul_rn(zz,zz));
    }
    __syncthreads();
    for(int s = widb; s < Sc; s += 31){
      if(tid==0){
        int qn;
        for(;;){
          qn = __hip_atomic_load(&fps_idx[b*Sc + s], __ATOMIC_RELAXED, __HIP_MEMORY_SCOPE_AGENT);
          if(qn >= 0) break;
          __builtin_amdgcn_s_sleep(8);
        }
        s_qn[0] = qn & (Nc-1);
      }
      bar_lds();
      int qn = s_qn[0];
      const float* q = xyz + ((size_t)b*Nc + qn)*3;
      float sxq = q[0], syq = q[1], szq = q[2];
      if(tid < 3) out0[((size_t)b*Sc + s)*3 + tid] = q[tid];
      float ss = __fadd_rn(__fadd_rn(__fmul_rn(sxq,sxq),__fmul_rn(syq,syq)),__fmul_rn(szq,szq));
      float dv[8];
#pragma unroll
      for(int j=0;j<8;j++){
        float e = __fmul_rn(sxq,px[j]);
        e = __fadd_rn(e, __fmul_rn(syq,py[j]));
        e = __fadd_rn(e, __fmul_rn(szq,pz[j]));
        dv[j] = __fadd_rn(__fadd_rn(__fmul_rn(-2.f,e), ss), db[j]);
      }
      int* ob = knn_idx + ((size_t)b*Sc + s)*Kc;
      for(int k=0;k<Kc;k++){
        float bvv = dv[0];
#pragma unroll
        for(int j=1;j<8;j++) bvv = fminf(bvv, dv[j]);
        bvv = dpp_min_f32<0x111>(bvv);
        bvv = dpp_min_f32<0x112>(bvv);
        bvv = dpp_min_f32<0x114>(bvv);
        bvv = dpp_min_f32<0x118>(bvv);
        bvv = dpp_min_f32<0x142>(bvv);
        bvv = dpp_min_f32<0x143>(bvv);
        if((tid&63)==63) pv[tid>>6] = bvv;
        bar_lds();
        float vmin = fminf(fminf(fminf(pv[0],pv[1]), fminf(pv[2],pv[3])),
                           fminf(fminf(pv[4],pv[5]), fminf(pv[6],pv[7])));
        unsigned bi = 0xFFFFFFFFu;
#pragma unroll
        for(int j=0;j<8;j++){
          unsigned n = (unsigned)(tid + 512*j);
          if(dv[j]==vmin && n < bi) bi = n;
        }
        bi = dpp_min_u32<0x111>(bi);
        bi = dpp_min_u32<0x112>(bi);
        bi = dpp_min_u32<0x114>(bi);
        bi = dpp_min_u32<0x118>(bi);
        bi = dpp_min_u32<0x142>(bi);
        bi = dpp_min_u32<0x143>(bi);
        if((tid&63)==63) pi[tid>>6] = (int)bi;
        bar_lds();
        unsigned win = (unsigned)pi[0];
#pragma unroll
        for(int w=1;w<8;w++){ unsigned u=(unsigned)pi[w]; win = u<win?u:win; }
        if(tid==0) ob[k] = (int)(win & (Nc-1));
#pragma unroll
        for(int j=0;j<8;j++) if((int)win == tid + 512*j) dv[j] = 3.4e38f;
      }
    }
  }
}

// ------- local_fused: proj + l1 + (l2 + residual + gelu + k-max) ----------
// One block = 48 rows (2 s-groups of Kc=24), full N=256. 4 waves, wave w owns
// cols [64w,64w+64). All intermediates (H, R) live in LDS -> eliminates the
// 4x96MB hbuf/rbuf round-trips of the 3-kernel pipeline. Arithmetic order
// (k-ascending MFMA accumulation, identical epilogue formulas, bf16
// intermediate storage) matches the original kernels bit-exactly.
__global__ __launch_bounds__(256) void local_fused(
    const short* __restrict__ xT, const int* __restrict__ knn_idx, const int* __restrict__ fps_idx,
    const short* __restrict__ Wp_, const float* __restrict__ gp, const float* __restrict__ bp,
    const short* __restrict__ W1, const float* __restrict__ g1, const float* __restrict__ b1,
    const short* __restrict__ W2, const float* __restrict__ g2, const float* __restrict__ b2,
    short* __restrict__ Fout){
  // LDS: Asrc [4][48][32] @0 (12288B) | Wst [256][32] @12288 (16384B)
  //      Hb [8][48][32] @28672 (24576B) | Rb [8][48][32] @53248 (24576B) = 77824B
  __shared__ __align__(16) char lds[77824];
  short* Asrc = (short*)lds;
  short* Wst  = (short*)(lds + 12288);
  short* Hb   = (short*)(lds + 28672);
  short* Rb   = (short*)(lds + 53248);
  int p = blockIdx.x;             // 0..4095
  int R0 = p*48;
  int tid = threadIdx.x;
  int w = tid >> 6, lane = tid & 63, quad = lane >> 4, l16 = lane & 15;
  int colbase = w*64;
  // ---- edge gather: [48][128] -> Asrc (k-block-major [kb][row][32]) ----
#pragma unroll
  for(int u0=0; u0<3; u0++){
    int u = tid + u0*256;         // 768 units: (row, seg8)
    int r = u >> 4, seg = u & 15;
    int Rg = R0 + r;
    int bb = Rg / MBAT;
    int nk = knn_idx[Rg] & (Nc-1);
    int nc = fps_idx[Rg / Kc] & (Nc-1);
    bf16x8 vk = *(const bf16x8*)(xT + ((size_t)bb*Nc + nk)*CINc + seg*8);
    bf16x8 vc = *(const bf16x8*)(xT + ((size_t)bb*Nc + nc)*CINc + seg*8);
    bf16x8 e;
#pragma unroll
    for(int i=0;i<8;i++) e[i] = f2b(__fsub_rn(b2f(vk[i]), b2f(vc[i])));
    *(bf16x8*)&Asrc[((seg>>2)*48 + r)*32 + (seg&3)*8] = e;
  }
  __syncthreads();
  f32x4 acc[3][4];
  // ================= stage 1: H = gelu(bn(edge @ Wproj^T)) =================
#pragma unroll
  for(int mt=0;mt<3;mt++)
#pragma unroll
    for(int nt=0;nt<4;nt++) acc[mt][nt] = (f32x4){0.f,0.f,0.f,0.f};
  for(int k0=0; k0<CINc; k0+=32){
#pragma unroll
    for(int c=0;c<4;c++)
      gl_lds16(Wp_ + (size_t)(c*64 + (tid>>2))*CINc + k0 + (tid&3)*8,
               Wst + c*2048 + tid*8);
    __syncthreads();
    bf16x8 af[3], bfr[4];
#pragma unroll
    for(int mt=0;mt<3;mt++) af[mt] = *(const bf16x8*)&Asrc[(((k0>>5))*48 + mt*16 + l16)*32 + quad*8];
#pragma unroll
    for(int nt=0;nt<4;nt++) bfr[nt] = *(const bf16x8*)&Wst[(colbase + nt*16 + l16)*32 + quad*8];
#pragma unroll
    for(int mt=0;mt<3;mt++)
#pragma unroll
      for(int nt=0;nt<4;nt++)
        acc[mt][nt] = __builtin_amdgcn_mfma_f32_16x16x32_bf16(af[mt], bfr[nt], acc[mt][nt], 0, 0, 0);
    __syncthreads();
  }
#pragma unroll
  for(int nt=0;nt<4;nt++){
    int col = colbase + nt*16 + l16;
    float gs = gp[col] * BN_SCALE_F, bs_ = bp[col];
    int kb = col >> 5, kr = col & 31;
#pragma unroll
    for(int mt=0;mt<3;mt++)
#pragma unroll
      for(int r2=0;r2<4;r2++){
        int row = mt*16 + quad*4 + r2;
        float v = acc[mt][nt][r2]*gs + bs_;
        Hb[(kb*48 + row)*32 + kr] = f2b(gelu_f(v));
      }
  }
  __syncthreads();
  // ================= stage 2: R = gelu(bn(H @ Wl1^T)) ======================
#pragma unroll
  for(int mt=0;mt<3;mt++)
#pragma unroll
    for(int nt=0;nt<4;nt++) acc[mt][nt] = (f32x4){0.f,0.f,0.f,0.f};
  for(int k0=0; k0<COUTc; k0+=32){
#pragma unroll
    for(int c=0;c<4;c++)
      gl_lds16(W1 + (size_t)(c*64 + (tid>>2))*COUTc + k0 + (tid&3)*8,
               Wst + c*2048 + tid*8);
    __syncthreads();
    bf16x8 af[3], bfr[4];
#pragma unroll
    for(int mt=0;mt<3;mt++) af[mt] = *(const bf16x8*)&Hb[(((k0>>5))*48 + mt*16 + l16)*32 + quad*8];
#pragma unroll
    for(int nt=0;nt<4;nt++) bfr[nt] = *(const bf16x8*)&Wst[(colbase + nt*16 + l16)*32 + quad*8];
#pragma unroll
    for(int mt=0;mt<3;mt++)
#pragma unroll
      for(int nt=0;nt<4;nt++)
        acc[mt][nt] = __builtin_amdgcn_mfma_f32_16x16x32_bf16(af[mt], bfr[nt], acc[mt][nt], 0, 0, 0);
    __syncthreads();
  }
#pragma unroll
  for(int nt=0;nt<4;nt++){
    int col = colbase + nt*16 + l16;
    float gs = g1[col] * BN_SCALE_F, bs_ = b1[col];
    int kb = col >> 5, kr = col & 31;
#pragma unroll
    for(int mt=0;mt<3;mt++)
#pragma unroll
      for(int r2=0;r2<4;r2++){
        int row = mt*16 + quad*4 + r2;
        float v = acc[mt][nt][r2]*gs + bs_;
        Rb[(kb*48 + row)*32 + kr] = f2b(gelu_f(v));
      }
  }
  __syncthreads();
  // ========= stage 3: F = max_k gelu(bn(R @ Wl2^T) + H), per group =========
#pragma unroll
  for(int mt=0;mt<3;mt++)
#pragma unroll
    for(int nt=0;nt<4;nt++) acc[mt][nt] = (f32x4){0.f,0.f,0.f,0.f};
  for(int k0=0; k0<COUTc; k0+=32){
#pragma unroll
    for(int c=0;c<4;c++)
      gl_lds16(W2 + (size_t)(c*64 + (tid>>2))*COUTc + k0 + (tid&3)*8,
               Wst + c*2048 + tid*8);
    __syncthreads();
    bf16x8 af[3], bfr[4];
#pragma unroll
    for(int mt=0;mt<3;mt++) af[mt] = *(const bf16x8*)&Rb[(((k0>>5))*48 + mt*16 + l16)*32 + quad*8];
#pragma unroll
    for(int nt=0;nt<4;nt++) bfr[nt] = *(const bf16x8*)&Wst[(colbase + nt*16 + l16)*32 + quad*8];
#pragma unroll
    for(int mt=0;mt<3;mt++)
#pragma unroll
      for(int nt=0;nt<4;nt++)
        acc[mt][nt] = __builtin_amdgcn_mfma_f32_16x16x32_bf16(af[mt], bfr[nt], acc[mt][nt], 0, 0, 0);
    __syncthreads();
  }
  // epilogue: bn + residual(H) + gelu, then max over k=24 rows per group.
  // rows 0..23 -> group p*2, rows 24..47 -> group p*2+1. Per lane partition:
  // mt0 all -> g0; mt2 all -> g1; mt1: quad<2 -> g0 else g1. Cross-quad via shfl.
#pragma unroll
  for(int nt=0;nt<4;nt++){
    int col = colbase + nt*16 + l16;
    float gs = g2[col] * BN_SCALE_F, bs_ = b2[col];
    int kb = col >> 5, kr = col & 31;
    float gm0 = -3.4e38f, gm1 = -3.4e38f;
#pragma unroll
    for(int mt=0;mt<3;mt++)
#pragma unroll
      for(int r2=0;r2<4;r2++){
        int row = mt*16 + quad*4 + r2;
        float v = acc[mt][nt][r2]*gs + bs_;
        v += b2f(Hb[(kb*48 + row)*32 + kr]);
        v = gelu_f(v);
        if(mt==0) gm0 = fmaxf(gm0, v);
        else if(mt==2) gm1 = fmaxf(gm1, v);
        else { if(quad < 2) gm0 = fmaxf(gm0, v); else gm1 = fmaxf(gm1, v); }
      }
    gm0 = fmaxf(gm0, __shfl_xor(gm0, 16));
    gm0 = fmaxf(gm0, __shfl_xor(gm0, 32));
    gm1 = fmaxf(gm1, __shfl_xor(gm1, 16));
    gm1 = fmaxf(gm1, __shfl_xor(gm1, 32));
    if(quad == 0){
      Fout[(size_t)(p*2)*COUTc + col]     = f2b(gm0);
      Fout[(size_t)(p*2+1)*COUTc + col]   = f2b(gm1);
    }
  }
}

// ------- 64x64 MFMA GEMM, A & W bf16, both staged via global_load_lds ------
template<int HAS_BN, int HAS_GELU, int HAS_RES, typename TRES, typename TOUT>
__global__ __launch_bounds__(256) void gemm64d(
    const short* __restrict__ A, const short* __restrict__ W,
    const float* __restrict__ g, const float* __restrict__ bias,
    const TRES* __restrict__ Res, TOUT* __restrict__ Out,
    int Nn, int Kk){
  __shared__ short As[64*32];
  __shared__ short Bs[64*32];
  int bm = blockIdx.y*64, bn = blockIdx.x*64;
  int tid = threadIdx.x;
  int wave = tid >> 6, lane = tid & 63, quad = lane >> 4, l16 = lane & 15;
  f32x4 acc[4];
#pragma unroll
  for(int i=0;i<4;i++) acc[i] = (f32x4){0.f,0.f,0.f,0.f};
  const short* Ap = A + (size_t)(bm + (tid>>2))*Kk + (tid&3)*8;
  const short* Wp = W + (size_t)(bn + (tid>>2))*Kk + (tid&3)*8;
  for(int k0=0; k0<Kk; k0+=32){
    gl_lds16(Ap + k0, As + tid*8);
    gl_lds16(Wp + k0, Bs + tid*8);
    __syncthreads();
    bf16x8 a = *(const bf16x8*)&As[(wave*16 + l16)*32 + quad*8];
#pragma unroll
    for(int ct=0; ct<4; ct++){
      bf16x8 bb = *(const bf16x8*)&Bs[(ct*16 + l16)*32 + quad*8];
      acc[ct] = __builtin_amdgcn_mfma_f32_16x16x32_bf16(a, bb, acc[ct], 0, 0, 0);
    }
    __syncthreads();
  }
#pragma unroll
  for(int ct=0; ct<4; ct++){
    int col = bn + ct*16 + l16;
    float gs = 0.f, bs_ = 0.f;
    if(HAS_BN){ gs = g[col] * BN_SCALE_F; bs_ = bias[col]; }
#pragma unroll
    for(int r2=0;r2<4;r2++){
      int row = bm + wave*16 + quad*4 + r2;
      float v = acc[ct][r2];
      if(HAS_BN) v = v*gs + bs_;
      if(HAS_RES) v += rdval(Res + (size_t)row*Nn + col);
      if(HAS_GELU) v = gelu_f(v);
      wrval(Out + (size_t)row*Nn + col, v);
    }
  }
}

// ---------------- f2 [B,S,C] bf16 -> x_out [B,C,S] f32 ---------------------
__global__ __launch_bounds__(256) void transpose_f(const short* __restrict__ f2, float* __restrict__ out1){
  __shared__ short tile[32][33];
  int b = blockIdx.z;
  int s0 = blockIdx.x*32, c0 = blockIdx.y*32;
  int tx = threadIdx.x & 31, ty = threadIdx.x >> 5;
#pragma unroll
  for(int i=0;i<32;i+=8)
    tile[ty+i][tx] = f2[((size_t)b*Sc + (s0+ty+i))*COUTc + c0+tx];
  __syncthreads();
#pragma unroll
  for(int i=0;i<32;i+=8)
    out1[((size_t)b*COUTc + (c0+ty+i))*Sc + s0+tx] = b2f(tile[tx][ty+i]);
}

// ------- Local2Former attention: block per (b,m); kv packed [row,512] ------
__global__ __launch_bounds__(256) void l2f_attn(
    const short* __restrict__ qb, const short* __restrict__ kv,
    short* __restrict__ ao){
  int blk = blockIdx.x; int b = blk / Mc; int m = blk % Mc;
  int tid = threadIdx.x;
  __shared__ float qs[TCHc];
  __shared__ float aw[Sc];
  __shared__ float red[8];
  qs[tid] = b2f(qb[(size_t)(b*Mc+m)*TCHc + tid]);
  __syncthreads();
  float sc[4];
#pragma unroll
  for(int jj=0;jj<4;jj++){
    int j = tid + 256*jj;
    const short* kp = kv + ((size_t)b*Sc + j)*512;
    float a = 0.f;
    for(int c=0;c<TCHc;c+=8){
      bf16x8 v8 = *(const bf16x8*)(kp + c);
#pragma unroll
      for(int i=0;i<8;i++) a += b2f(v8[i]) * qs[c+i];
    }
    sc[jj] = a * 0.0625f;   // TCH^-0.5
  }
  float mx = fmaxf(fmaxf(sc[0],sc[1]), fmaxf(sc[2],sc[3]));
#pragma unroll
  for(int off=32; off>0; off>>=1) mx = fmaxf(mx, __shfl_xor(mx, off));
  if((tid&63)==0) red[tid>>6] = mx;
  __syncthreads();
  mx = fmaxf(fmaxf(red[0],red[1]), fmaxf(red[2],red[3]));
  float se = 0.f;
#pragma unroll
  for(int jj=0;jj<4;jj++){
    float e = expf(sc[jj] - mx);
    aw[tid + 256*jj] = e;
    se += e;
  }
#pragma unroll
  for(int off=32; off>0; off>>=1) se += __shfl_xor(se, off);
  if((tid&63)==0) red[4 + (tid>>6)] = se;
  __syncthreads();
  se = red[4]+red[5]+red[6]+red[7];
  float inv = 1.f/se;
#pragma unroll
  for(int jj=0;jj<4;jj++) aw[tid + 256*jj] *= inv;
  __syncthreads();
  float acc = 0.f;
  const short* vp = kv + (size_t)b*Sc*512 + 256 + tid;
  for(int j=0;j<Sc;j++) acc += aw[j] * b2f(vp[(size_t)j*512]);
  ao[(size_t)(b*Mc+m)*TCHc + tid] = f2b(acc);
}

// ---------------- Former MHA: block per (b,h,m), 64 threads ----------------
__global__ __launch_bounds__(64) void former_attn(const short* __restrict__ qkv, short* __restrict__ oa){
  int blk = blockIdx.x;
  int m = blk % Mc; int bh = blk / Mc; int h = bh % Hc; int b = bh / Hc;
  int lane = threadIdx.x;
  __shared__ float qs[HDc];
  __shared__ float aw2[32];
  const short* base = qkv + (size_t)(b*Mc)*(3*TCHc);
  qs[lane] = b2f(base[(size_t)m*3*TCHc + h*HDc + lane]);
  __syncthreads();
  int j = lane & 31;
  const short* kp = base + (size_t)j*3*TCHc + TCHc + h*HDc;
  float s = 0.f;
  for(int d=0; d<HDc; d+=8){
    bf16x8 v8 = *(const bf16x8*)(kp + d);
#pragma unroll
    for(int i=0;i<8;i++) s += b2f(v8[i]) * qs[d+i];
  }
  s *= 0.125f;  // HD^-0.5
  float mx = s;
#pragma unroll
  for(int off=16; off>0; off>>=1) mx = fmaxf(mx, __shfl_xor(mx, off, 32));
  float e = expf(s - mx);
  float se = e;
#pragma unroll
  for(int off=16; off>0; off>>=1) se += __shfl_xor(se, off, 32);
  if(lane < 32) aw2[lane] = e / se;
  __syncthreads();
  float acc = 0.f;
  const short* vp = base + 2*TCHc + h*HDc + lane;
  for(int jj=0; jj<32; jj++) acc += aw2[jj] * b2f(vp[(size_t)jj*3*TCHc]);
  oa[(size_t)(b*Mc+m)*TCHc + h*HDc + lane] = f2b(acc);
}

// ---------------- LayerNorm over 256: f32 in, bf16 out ---------------------
__global__ __launch_bounds__(64) void ln_kernel(const float* __restrict__ X, const float* __restrict__ g,
                                                const float* __restrict__ bb, short* __restrict__ O){
  int row = blockIdx.x, lane = threadIdx.x;
  const float* xp = X + (size_t)row*TCHc;
  float x[4];
#pragma unroll
  for(int j2=0;j2<4;j2++) x[j2] = xp[lane + 64*j2];
  float sm = x[0]+x[1]+x[2]+x[3];
#pragma unroll
  for(int off=32; off>0; off>>=1) sm += __shfl_xor(sm, off);
  float mu = sm * (1.f/256.f);
  float vs = 0.f;
#pragma unroll
  for(int j2=0;j2<4;j2++){ float d = x[j2]-mu; vs += d*d; }
#pragma unroll
  for(int off=32; off>0; off>>=1) vs += __shfl_xor(vs, off);
  float var = vs * (1.f/256.f);
  float rstd = 1.f / sqrtf(var + 1e-5f);
#pragma unroll
  for(int j2=0;j2<4;j2++){
    int c = lane + 64*j2;
    float o = (x[j2]-mu)*rstd*g[c] + bb[c];
    O[(size_t)row*TCHc + c] = f2b(o);
  }
}

extern "C" void kernel_launch(void* const* d_in, const int* in_sizes, int n_in,
                              void* d_out, int out_size, void* d_ws, size_t ws_size,
                              hipStream_t stream){
  const float* xyz  = (const float*)d_in[0];
  const float* x    = (const float*)d_in[1];
  const float* t_in = (const float*)d_in[2];
  const int*   far0 = (const int*)d_in[3];
  const float* Wproj=(const float*)d_in[4];  const float* gproj=(const float*)d_in[5];  const float* bproj=(const float*)d_in[6];
  const float* Wl1 = (const float*)d_in[7];  const float* gl1 = (const float*)d_in[8];  const float* bl1 = (const float*)d_in[9];
  const float* Wl2 = (const float*)d_in[10]; const float* gl2 = (const float*)d_in[11]; const float* bl2 = (const float*)d_in[12];
  const float* Wc1 = (const float*)d_in[13]; const float* gc1 = (const float*)d_in[14]; const float* bc1 = (const float*)d_in[15];
  const float* Wc2 = (const float*)d_in[16]; const float* gc2 = (const float*)d_in[17]; const float* bc2 = (const float*)d_in[18];
  const float* Wq  = (const float*)d_in[19]; const float* Wk  = (const float*)d_in[20]; const float* Wv  = (const float*)d_in[21];
  const float* Wo  = (const float*)d_in[22];
  const float* ln1g= (const float*)d_in[23]; const float* ln1b= (const float*)d_in[24];
  const float* Wqkv= (const float*)d_in[25]; const float* Wao = (const float*)d_in[26];
  const float* ln2g= (const float*)d_in[27]; const float* ln2b= (const float*)d_in[28];
  const float* Wf1 = (const float*)d_in[29]; const float* Wf2 = (const float*)d_in[30];

  char* wsb = (char*)d_ws;
  size_t off = 0;
  auto alloc = [&](size_t bytes)->void*{ void* p = wsb + off; off += (bytes + 255) & ~(size_t)255; return p; };
  int*   fps_i = (int*)alloc((size_t)Bc*Sc*4);
  int*   knn   = (int*)alloc((size_t)Bc*Sc*Kc*4);
  short* xT    = (short*)alloc((size_t)Bc*Nc*CINc*2);
  // bf16 pool: proj,l1,l2,c1,c2,k,v,q,o,qkv,ao,f1,f2,t
  size_t wbf_elems = (size_t)COUTc*CINc + 4*(size_t)COUTc*COUTc + 2*(size_t)TCHc*COUTc
                   + 2*(size_t)TCHc*TCHc + 3*(size_t)TCHc*TCHc + (size_t)TCHc*TCHc
                   + 2*(size_t)TCHc*TCHc + 2*(size_t)TCHc*TCHc + (size_t)Bc*Mc*TCHc;
  short* wbf   = (short*)alloc(wbf_elems*2);
  short* fbuf  = (short*)alloc((size_t)Bc*Sc*COUTc*2);
  short* rcbuf = (short*)alloc((size_t)Bc*Sc*COUTc*2);
  short* f2buf = (short*)alloc((size_t)Bc*Sc*COUTc*2);
  short* kvbuf = (short*)alloc((size_t)Bc*Sc*512*2);
  short* qbuf  = (short*)alloc((size_t)Bc*Mc*TCHc*2);
  short* a1out = (short*)alloc((size_t)Bc*Mc*TCHc*2);
  float* t1buf = (float*)alloc((size_t)Bc*Mc*TCHc*4);
  short* hnbuf = (short*)alloc((size_t)Bc*Mc*TCHc*2);
  short* qkvb  = (short*)alloc((size_t)Bc*Mc*3*TCHc*2);
  short* a2out = (short*)alloc((size_t)Bc*Mc*TCHc*2);
  float* t2buf = (float*)alloc((size_t)Bc*Mc*TCHc*4);
  short* hn2buf= (short*)alloc((size_t)Bc*Mc*TCHc*2);
  short* g1buf = (short*)alloc((size_t)Bc*Mc*2*TCHc*2);
  if(off > ws_size) return;  // insufficient workspace; fail visibly

  short* wproj_bf = wbf;
  short* wl1_bf   = wproj_bf + COUTc*CINc;
  short* wl2_bf   = wl1_bf + COUTc*COUTc;
  short* wc1_bf   = wl2_bf + COUTc*COUTc;
  short* wc2_bf   = wc1_bf + COUTc*COUTc;
  short* wkv_bf   = wc2_bf + COUTc*COUTc;     // [512,256]
  short* wq_bf    = wkv_bf + 2*TCHc*COUTc;
  short* wo_bf    = wq_bf + TCHc*TCHc;
  short* wqkv_bf  = wo_bf + TCHc*TCHc;
  short* wao_bf   = wqkv_bf + 3*TCHc*TCHc;
  short* wf1_bf   = wao_bf + TCHc*TCHc;
  short* wf2_bf   = wf1_bf + 2*TCHc*TCHc;
  short* tbf      = wf2_bf + 2*TCHc*TCHc;     // t_in as bf16

  float* out0 = (float*)d_out;
  float* out1 = out0 + (size_t)Bc*Sc*3;
  float* out2 = out1 + (size_t)Bc*COUTc*Sc;

  // --- prep+knn: fps publishes winners (relaxed); workers poll fps_idx ---
  hipMemsetAsync(fps_i, 0xFF, (size_t)Bc*Sc*4, stream);   // sentinel: -1 = not yet written
  prep_kernel<<<PREP_TOTAL, 512, 0, stream>>>(xyz, far0, fps_i, x, xT,
                                              Wproj, Wl1, Wl2, Wc1, Wc2, Wk, Wv,
                                              Wq, Wo, Wqkv, Wao, Wf1, Wf2, t_in,
                                              wbf, knn, out0);
  // --- Local: fused proj + l1 + (l2 + residual + gelu + k-max) ---
  local_fused<<<(Bc*Sc)/2, 256, 0, stream>>>(xT, knn, fps_i,
                                             wproj_bf, gproj, bproj,
                                             wl1_bf, gl1, bl1,
                                             wl2_bf, gl2, bl2, fbuf);
  // --- Channel ---
  gemm64d<1,1,0,short,short><<<dim3(COUTc/64, (Bc*Sc)/64), 256, 0, stream>>>(fbuf, wc1_bf, gc1, bc1, (const short*)nullptr, rcbuf, COUTc, COUTc);
  gemm64d<1,1,1,short,short><<<dim3(COUTc/64, (Bc*Sc)/64), 256, 0, stream>>>(rcbuf, wc2_bf, gc2, bc2, fbuf, f2buf, COUTc, COUTc);
  transpose_f<<<dim3(Sc/32, COUTc/32, Bc), 256, 0, stream>>>(f2buf, out1);
  // --- Local2Former ---
  gemm64d<0,0,0,short,short><<<dim3(TCHc/64, (Bc*Mc)/64), 256, 0, stream>>>(tbf, wq_bf, nullptr, nullptr, (const short*)nullptr, qbuf, TCHc, TCHc);
  gemm64d<0,0,0,short,short><<<dim3(512/64, (Bc*Sc)/64), 256, 0, stream>>>(f2buf, wkv_bf, nullptr, nullptr, (const short*)nullptr, kvbuf, 512, COUTc);
  l2f_attn<<<Bc*Mc, 256, 0, stream>>>(qbuf, kvbuf, a1out);
  gemm64d<0,0,1,float,float><<<dim3(TCHc/64, (Bc*Mc)/64), 256, 0, stream>>>(a1out, wo_bf, nullptr, nullptr, t_in, t1buf, TCHc, TCHc);
  // --- Former ---
  ln_kernel<<<Bc*Mc, 64, 0, stream>>>(t1buf, ln1g, ln1b, hnbuf);
  gemm64d<0,0,0,short,short><<<dim3((3*TCHc)/64, (Bc*Mc)/64), 256, 0, stream>>>(hnbuf, wqkv_bf, nullptr, nullptr, (const short*)nullptr, qkvb, 3*TCHc, TCHc);
  former_attn<<<Bc*Hc*Mc, 64, 0, stream>>>(qkvb, a2out);
  gemm64d<0,0,1,float,float><<<dim3(TCHc/64, (Bc*Mc)/64), 256, 0, stream>>>(a2out, wao_bf, nullptr, nullptr, t1buf, t2buf, TCHc, TCHc);
  ln_kernel<<<Bc*Mc, 64, 0, stream>>>(t2buf, ln2g, ln2b, hn2buf);
  gemm64d<0,1,0,short,short><<<dim3((2*TCHc)/64, (Bc*Mc)/64), 256, 0, stream>>>(hn2buf, wf1_bf, nullptr, nullptr, (const short*)nullptr, g1buf, 2*TCHc, TCHc);
  gemm64d<0,0,1,float,float><<<dim3(TCHc/64, (Bc*Mc)/64), 256, 0, stream>>>(g1buf, wf2_bf, nullptr, nullptr, t2buf, out2, TCHc, 2*TCHc);
}